// Round 1
// baseline (532.126 us; speedup 1.0000x reference)
//
#include <hip/hip_runtime.h>
#include <hip/hip_bf16.h>
#include <stdint.h>
#include <type_traits>

typedef __attribute__((ext_vector_type(4))) float   f32x4;
typedef __attribute__((ext_vector_type(8))) __bf16  bf16x8;
typedef __attribute__((ext_vector_type(8))) unsigned short u16x8;

#define B_   2
#define S_   2048
#define DIM_ 2048
#define NH_  16
#define NKV_ 8
#define HD_  128

__device__ inline unsigned short f2bf(float f) {
    unsigned u = __float_as_uint(f);
    unsigned r = (u + 0x7fffu + ((u >> 16) & 1u)) >> 16;
    return (unsigned short)r;
}
__device__ inline float bf2f(unsigned short s) {
    return __uint_as_float(((unsigned)s) << 16);
}

// ---------------- fused fp32 -> bf16 convert (x, wq, wk, wv, wo) ----------------
__global__ void k_convert(const float* __restrict__ x,  const float* __restrict__ wq,
                          const float* __restrict__ wk, const float* __restrict__ wv,
                          const float* __restrict__ wo,
                          unsigned short* __restrict__ xb,  unsigned short* __restrict__ wqb,
                          unsigned short* __restrict__ wkb, unsigned short* __restrict__ wvb,
                          unsigned short* __restrict__ wob)
{
    int i = blockIdx.x * blockDim.x + threadIdx.x;  // quad index
    const int NX = 2097152, NWQ = 1048576, NWK = 524288, NWV = 524288, NWO = 1048576;
    const float* src; unsigned short* dst; int j = i;
    if (j < NX) { src = x; dst = xb; }
    else {
        j -= NX;
        if (j < NWQ) { src = wq; dst = wqb; }
        else {
            j -= NWQ;
            if (j < NWK) { src = wk; dst = wkb; }
            else {
                j -= NWK;
                if (j < NWV) { src = wv; dst = wvb; }
                else { j -= NWV; if (j >= NWO) return; src = wo; dst = wob; }
            }
        }
    }
    float4 v = reinterpret_cast<const float4*>(src)[j];
    ushort4 o;
    o.x = f2bf(v.x); o.y = f2bf(v.y); o.z = f2bf(v.z); o.w = f2bf(v.w);
    reinterpret_cast<ushort4*>(dst)[j] = o;
}

// ---------------- RoPE cos/sin table: [S][64] pairs ----------------
__global__ void k_rope_table(float* __restrict__ tab)
{
    int t = blockIdx.x * blockDim.x + threadIdx.x;  // s*64 + i
    if (t >= S_ * 64) return;
    int i = t & 63;
    int s = t >> 6;
    // inv = 10000^(-i/64)
    float inv = expf(-((float)i / 64.0f) * 9.210340371976184f);  // ln(10000)
    float ang = (float)s * inv;
    tab[2 * t]     = cosf(ang);
    tab[2 * t + 1] = sinf(ang);
}

// ---------------- in-place RoPE on bf16 Q and K ----------------
__global__ void k_rope(unsigned short* __restrict__ Qb, unsigned short* __restrict__ Kb,
                       const float* __restrict__ tab)
{
    int t = blockIdx.x * blockDim.x + threadIdx.x;
    const int NQ = B_ * S_ * NH_ * 64;    // 4194304 pairs
    const int NK = B_ * S_ * NKV_ * 64;   // 2097152 pairs
    unsigned short* p; int i, s;
    if (t < NQ) {
        p = Qb + (size_t)t * 2;
        i = t & 63;
        s = (t >> (6 + 4)) & (S_ - 1);    // H=16 -> 4 bits
    } else {
        int t2 = t - NQ;
        if (t2 >= NK) return;
        p = Kb + (size_t)t2 * 2;
        i = t2 & 63;
        s = (t2 >> (6 + 3)) & (S_ - 1);   // HK=8 -> 3 bits
    }
    float c  = tab[(s * 64 + i) * 2];
    float sn = tab[(s * 64 + i) * 2 + 1];
    ushort2 v = *reinterpret_cast<ushort2*>(p);
    float xr = bf2f(v.x), xi = bf2f(v.y);
    ushort2 o;
    o.x = f2bf(xr * c - xi * sn);
    o.y = f2bf(xr * sn + xi * c);
    *reinterpret_cast<ushort2*>(p) = o;
}

// ---------------- bf16 GEMM, C = A(MxK) * B(NxK)^T, m97 structure ----------------
// 128x128 tile, BK=64, 256 threads (4 waves as 2x2 of 64x64), global_load_lds staging.
template <typename OUT_T>
__global__ __launch_bounds__(256) void k_gemm_bt(
    const unsigned short* __restrict__ A,
    const unsigned short* __restrict__ Bm,
    OUT_T* __restrict__ C, int M, int N, int K)
{
    __shared__ __attribute__((aligned(16))) unsigned short As[128 * 64];
    __shared__ __attribute__((aligned(16))) unsigned short Bs[128 * 64];

    const int tid  = threadIdx.x;
    const int lane = tid & 63;
    const int wid  = tid >> 6;
    const int nbn  = N >> 7;
    const int brow = (blockIdx.x / nbn) << 7;
    const int bcol = (blockIdx.x % nbn) << 7;
    const int wr   = (wid >> 1) * 64;
    const int wc   = (wid & 1) * 64;
    const int g    = lane >> 4;
    const int lr   = lane & 15;

    f32x4 acc[4][4] = {};

    for (int k0 = 0; k0 < K; k0 += 64) {
        __syncthreads();
        #pragma unroll
        for (int i2 = 0; i2 < 4; ++i2) {
            int base = (i2 * 4 + wid) * 512;       // wave-uniform LDS elem offset
            int e = base + lane * 8;
            int r = e >> 6, c = e & 63;
            __builtin_amdgcn_global_load_lds(
                (const __attribute__((address_space(1))) void*)(A + (size_t)(brow + r) * K + k0 + c),
                (__attribute__((address_space(3))) void*)(As + base), 16, 0, 0);
            __builtin_amdgcn_global_load_lds(
                (const __attribute__((address_space(1))) void*)(Bm + (size_t)(bcol + r) * K + k0 + c),
                (__attribute__((address_space(3))) void*)(Bs + base), 16, 0, 0);
        }
        __syncthreads();
        #pragma unroll
        for (int kk = 0; kk < 2; ++kk) {
            bf16x8 af[4], bfv[4];
            #pragma unroll
            for (int m = 0; m < 4; ++m)
                af[m] = *reinterpret_cast<const bf16x8*>(&As[(wr + m * 16 + lr) * 64 + kk * 32 + g * 8]);
            #pragma unroll
            for (int n = 0; n < 4; ++n)
                bfv[n] = *reinterpret_cast<const bf16x8*>(&Bs[(wc + n * 16 + lr) * 64 + kk * 32 + g * 8]);
            #pragma unroll
            for (int m = 0; m < 4; ++m)
                #pragma unroll
                for (int n = 0; n < 4; ++n)
                    acc[m][n] = __builtin_amdgcn_mfma_f32_16x16x32_bf16(af[m], bfv[n], acc[m][n], 0, 0, 0);
        }
    }
    // epilogue: C/D layout col=lane&15, row=(lane>>4)*4+reg  [m89-verified]
    #pragma unroll
    for (int m = 0; m < 4; ++m) {
        #pragma unroll
        for (int n = 0; n < 4; ++n) {
            #pragma unroll
            for (int r = 0; r < 4; ++r) {
                int row = brow + wr + m * 16 + g * 4 + r;
                int col = bcol + wc + n * 16 + lr;
                float v = acc[m][n][r];
                if constexpr (std::is_same<OUT_T, float>::value)
                    C[(size_t)row * N + col] = v;
                else
                    C[(size_t)row * N + col] = f2bf(v);
            }
        }
    }
}

// ---------------- flash attention (causal, GQA) ----------------
// block = (b, h, 64 q-rows); 4 waves x 16 q-rows; KV tiles of 32.
__global__ __launch_bounds__(256) void k_attn(
    const unsigned short* __restrict__ Q,
    const unsigned short* __restrict__ Kg,
    const unsigned short* __restrict__ Vg,
    unsigned short* __restrict__ O)
{
    __shared__ __attribute__((aligned(16))) unsigned short Ks[32 * 128];   // XOR-swizzled (16B chunks)
    __shared__ __attribute__((aligned(16))) unsigned short Vt[128 * 40];   // V transposed, padded
    __shared__ __attribute__((aligned(16))) unsigned short Pl[4][16 * 56]; // per-wave P, padded

    const int tid  = threadIdx.x;
    const int lane = tid & 63;
    const int wid  = tid >> 6;
    const int g    = lane >> 4;
    const int lr   = lane & 15;

    int bid = blockIdx.x;
    const int nqt = S_ / 64;
    const int qt  = bid % nqt;  bid /= nqt;
    const int h   = bid % NH_;  bid /= NH_;
    const int b   = bid;
    const int hk  = h >> 1;

    const int q0 = qt * 64 + wid * 16;

    // Q fragments: A-layout row = lane&15, k = (lane>>4)*8 + j
    bf16x8 qf[4];
    {
        const size_t qb = ((size_t)(b * S_ + q0 + lr) * NH_ + h) * HD_;
        #pragma unroll
        for (int c = 0; c < 4; ++c)
            qf[c] = *reinterpret_cast<const bf16x8*>(Q + qb + c * 32 + g * 8);
    }

    f32x4 o_acc[8] = {};
    float m_run[4] = {-INFINITY, -INFINITY, -INFINITY, -INFINITY};
    float l_run[4] = {0.f, 0.f, 0.f, 0.f};

    const int nt = qt * 2 + 2;
    const float scale = 0.08838834764831845f;  // 1/sqrt(128)

    for (int t = 0; t < nt; ++t) {
        const int kv0 = t * 32;
        __syncthreads();  // previous iteration's PV reads done before restage

        // --- stage K tile 32x128 via global_load_lds, source pre-swizzled ---
        #pragma unroll
        for (int i2 = 0; i2 < 2; ++i2) {
            int base = (i2 * 4 + wid) * 512;
            int e = base + lane * 8;
            int r = e >> 7;
            int s = (e >> 3) & 15;
            int c = (s ^ (r & 15)) * 8;  // inverse-swizzle the global source column
            __builtin_amdgcn_global_load_lds(
                (const __attribute__((address_space(1))) void*)(Kg + ((size_t)(b * S_ + kv0 + r) * NKV_ + hk) * HD_ + c),
                (__attribute__((address_space(3))) void*)(Ks + base), 16, 0, 0);
        }
        // --- stage V tile transposed: Vt[d][kv], stride 40 ---
        {
            int r  = tid >> 3;
            int c0 = (tid & 7) * 16;
            const unsigned short* vs = Vg + ((size_t)(b * S_ + kv0 + r) * NKV_ + hk) * HD_ + c0;
            u16x8 v0 = *reinterpret_cast<const u16x8*>(vs);
            u16x8 v1 = *reinterpret_cast<const u16x8*>(vs + 8);
            #pragma unroll
            for (int j = 0; j < 8; ++j) Vt[(c0 + j) * 40 + r] = v0[j];
            #pragma unroll
            for (int j = 0; j < 8; ++j) Vt[(c0 + 8 + j) * 40 + r] = v1[j];
        }
        __syncthreads();

        // --- S = Q K^T (16x32), two 16x16 halves ---
        f32x4 sv[2];
        #pragma unroll
        for (int h2 = 0; h2 < 2; ++h2) {
            f32x4 a = {0.f, 0.f, 0.f, 0.f};
            #pragma unroll
            for (int c = 0; c < 4; ++c) {
                int row = h2 * 16 + lr;
                int sc  = c * 4 + g;
                bf16x8 kf = *reinterpret_cast<const bf16x8*>(&Ks[row * 128 + ((sc ^ (row & 15)) * 8)]);
                a = __builtin_amdgcn_mfma_f32_16x16x32_bf16(qf[c], kf, a, 0, 0, 0);
            }
            sv[h2] = a;
        }

        // --- scale + causal mask + tile row max ---
        float mt[4] = {-INFINITY, -INFINITY, -INFINITY, -INFINITY};
        #pragma unroll
        for (int h2 = 0; h2 < 2; ++h2) {
            int colg = kv0 + h2 * 16 + lr;
            #pragma unroll
            for (int r = 0; r < 4; ++r) {
                int rowg = q0 + g * 4 + r;
                float v = sv[h2][r] * scale;
                v = (colg <= rowg) ? v : -INFINITY;
                sv[h2][r] = v;
                mt[r] = fmaxf(mt[r], v);
            }
        }
        #pragma unroll
        for (int r = 0; r < 4; ++r) {
            #pragma unroll
            for (int off = 1; off < 16; off <<= 1)
                mt[r] = fmaxf(mt[r], __shfl_xor(mt[r], off));
        }

        float alpha[4], mn[4], rs[4];
        #pragma unroll
        for (int r = 0; r < 4; ++r) {
            mn[r] = fmaxf(m_run[r], mt[r]);
            alpha[r] = __expf(m_run[r] - mn[r]);   // first tile: exp(-inf)=0
            m_run[r] = mn[r];
            rs[r] = 0.f;
        }

        unsigned short pb[2][4];
        #pragma unroll
        for (int h2 = 0; h2 < 2; ++h2)
            #pragma unroll
            for (int r = 0; r < 4; ++r) {
                float p = __expf(sv[h2][r] - mn[r]);
                rs[r] += p;
                pb[h2][r] = f2bf(p);
            }
        #pragma unroll
        for (int r = 0; r < 4; ++r) {
            #pragma unroll
            for (int off = 1; off < 16; off <<= 1)
                rs[r] += __shfl_xor(rs[r], off);
            l_run[r] = l_run[r] * alpha[r] + rs[r];
        }
        #pragma unroll
        for (int c = 0; c < 8; ++c)
            #pragma unroll
            for (int r = 0; r < 4; ++r)
                o_acc[c][r] *= alpha[r];

        // --- P to LDS (C-layout -> A-layout round-trip) ---
        #pragma unroll
        for (int h2 = 0; h2 < 2; ++h2)
            #pragma unroll
            for (int r = 0; r < 4; ++r)
                Pl[wid][(g * 4 + r) * 56 + h2 * 16 + lr] = pb[h2][r];
        __syncthreads();

        // --- O += P V ---
        bf16x8 pa = *reinterpret_cast<const bf16x8*>(&Pl[wid][lr * 56 + g * 8]);
        #pragma unroll
        for (int c = 0; c < 8; ++c) {
            bf16x8 bv = *reinterpret_cast<const bf16x8*>(&Vt[(c * 16 + lr) * 40 + g * 8]);
            o_acc[c] = __builtin_amdgcn_mfma_f32_16x16x32_bf16(pa, bv, o_acc[c], 0, 0, 0);
        }
    }

    // epilogue: normalize and store (B,S,H,D) bf16
    float inv_l[4];
    #pragma unroll
    for (int r = 0; r < 4; ++r) inv_l[r] = 1.f / l_run[r];
    #pragma unroll
    for (int c = 0; c < 8; ++c)
        #pragma unroll
        for (int r = 0; r < 4; ++r) {
            int rowg = q0 + g * 4 + r;
            O[((size_t)(b * S_ + rowg) * NH_ + h) * HD_ + c * 16 + lr] = f2bf(o_acc[c][r] * inv_l[r]);
        }
}

// ---------------- launcher ----------------
extern "C" void kernel_launch(void* const* d_in, const int* in_sizes, int n_in,
                              void* d_out, int out_size, void* d_ws, size_t ws_size,
                              hipStream_t stream)
{
    const float* x  = (const float*)d_in[0];
    const float* wq = (const float*)d_in[1];
    const float* wk = (const float*)d_in[2];
    const float* wv = (const float*)d_in[3];
    const float* wo = (const float*)d_in[4];
    float* out = (float*)d_out;

    char* ws = (char*)d_ws;
    size_t off = 0;
    auto alloc = [&](size_t bytes) -> void* {
        void* p = ws + off;
        off += (bytes + 255) & ~(size_t)255;
        return p;
    };
    unsigned short* xb  = (unsigned short*)alloc((size_t)B_ * S_ * DIM_ * 2);
    unsigned short* wqb = (unsigned short*)alloc((size_t)DIM_ * DIM_ * 2);
    unsigned short* wkb = (unsigned short*)alloc((size_t)NKV_ * HD_ * DIM_ * 2);
    unsigned short* wvb = (unsigned short*)alloc((size_t)NKV_ * HD_ * DIM_ * 2);
    unsigned short* wob = (unsigned short*)alloc((size_t)DIM_ * DIM_ * 2);
    unsigned short* Qb  = (unsigned short*)alloc((size_t)B_ * S_ * NH_ * HD_ * 2);
    unsigned short* Kb  = (unsigned short*)alloc((size_t)B_ * S_ * NKV_ * HD_ * 2);
    unsigned short* Vb  = (unsigned short*)alloc((size_t)B_ * S_ * NKV_ * HD_ * 2);
    unsigned short* Ob  = (unsigned short*)alloc((size_t)B_ * S_ * NH_ * HD_ * 2);
    float* tab = (float*)alloc((size_t)S_ * 64 * 2 * 4);

    const int M = B_ * S_;  // 4096

    // 1) convert inputs to bf16
    k_convert<<<20480, 256, 0, stream>>>(x, wq, wk, wv, wo, xb, wqb, wkb, wvb, wob);
    // 2) RoPE table
    k_rope_table<<<(S_ * 64 + 255) / 256, 256, 0, stream>>>(tab);
    // 3) QKV projections
    k_gemm_bt<unsigned short><<<(M / 128) * (2048 / 128), 256, 0, stream>>>(xb, wqb, Qb, M, 2048, 2048);
    k_gemm_bt<unsigned short><<<(M / 128) * (1024 / 128), 256, 0, stream>>>(xb, wkb, Kb, M, 1024, 2048);
    k_gemm_bt<unsigned short><<<(M / 128) * (1024 / 128), 256, 0, stream>>>(xb, wvb, Vb, M, 1024, 2048);
    // 4) RoPE on Q and K (in-place)
    k_rope<<<(B_ * S_ * NH_ * 64 + B_ * S_ * NKV_ * 64 + 255) / 256, 256, 0, stream>>>(Qb, Kb, tab);
    // 5) attention
    k_attn<<<B_ * NH_ * (S_ / 64), 256, 0, stream>>>(Qb, Kb, Vb, Ob);
    // 6) output projection -> fp32
    k_gemm_bt<float><<<(M / 128) * (2048 / 128), 256, 0, stream>>>(Ob, wob, out, M, 2048, 2048);

    (void)in_sizes; (void)n_in; (void)out_size; (void)ws_size;
}

// Round 2
// 325.255 us; speedup vs baseline: 1.6360x; 1.6360x over previous
//
#include <hip/hip_runtime.h>
#include <hip/hip_bf16.h>
#include <stdint.h>
#include <type_traits>

typedef __attribute__((ext_vector_type(4))) float   f32x4;
typedef __attribute__((ext_vector_type(8))) __bf16  bf16x8;

#define B_   2
#define S_   2048
#define DIM_ 2048
#define NH_  16
#define NKV_ 8
#define HD_  128

__device__ inline unsigned short f2bf(float f) {
    unsigned u = __float_as_uint(f);
    unsigned r = (u + 0x7fffu + ((u >> 16) & 1u)) >> 16;
    return (unsigned short)r;
}
__device__ inline float bf2f(unsigned short s) {
    return __uint_as_float(((unsigned)s) << 16);
}

// ---------------- fused fp32 -> bf16 convert (x, wq, wk, wv, wo) ----------------
__global__ void k_convert(const float* __restrict__ x,  const float* __restrict__ wq,
                          const float* __restrict__ wk, const float* __restrict__ wv,
                          const float* __restrict__ wo,
                          unsigned short* __restrict__ xb,  unsigned short* __restrict__ wqb,
                          unsigned short* __restrict__ wkb, unsigned short* __restrict__ wvb,
                          unsigned short* __restrict__ wob)
{
    int i = blockIdx.x * blockDim.x + threadIdx.x;  // quad index
    const int NX = 2097152, NWQ = 1048576, NWK = 524288, NWV = 524288, NWO = 1048576;
    const float* src; unsigned short* dst; int j = i;
    if (j < NX) { src = x; dst = xb; }
    else {
        j -= NX;
        if (j < NWQ) { src = wq; dst = wqb; }
        else {
            j -= NWQ;
            if (j < NWK) { src = wk; dst = wkb; }
            else {
                j -= NWK;
                if (j < NWV) { src = wv; dst = wvb; }
                else { j -= NWV; if (j >= NWO) return; src = wo; dst = wob; }
            }
        }
    }
    float4 v = reinterpret_cast<const float4*>(src)[j];
    ushort4 o;
    o.x = f2bf(v.x); o.y = f2bf(v.y); o.z = f2bf(v.z); o.w = f2bf(v.w);
    reinterpret_cast<ushort4*>(dst)[j] = o;
}

// ---------------- RoPE cos/sin table: [S][64] pairs ----------------
__global__ void k_rope_table(float* __restrict__ tab)
{
    int t = blockIdx.x * blockDim.x + threadIdx.x;  // s*64 + i
    if (t >= S_ * 64) return;
    int i = t & 63;
    int s = t >> 6;
    float inv = expf(-((float)i / 64.0f) * 9.210340371976184f);  // 10000^(-i/64)
    float ang = (float)s * inv;
    tab[2 * t]     = cosf(ang);
    tab[2 * t + 1] = sinf(ang);
}

// ---------------- in-place RoPE on bf16 Q and K ----------------
__global__ void k_rope(unsigned short* __restrict__ Qb, unsigned short* __restrict__ Kb,
                       const float* __restrict__ tab)
{
    int t = blockIdx.x * blockDim.x + threadIdx.x;
    const int NQ = B_ * S_ * NH_ * 64;
    const int NK = B_ * S_ * NKV_ * 64;
    unsigned short* p; int i, s;
    if (t < NQ) {
        p = Qb + (size_t)t * 2;
        i = t & 63;
        s = (t >> (6 + 4)) & (S_ - 1);
    } else {
        int t2 = t - NQ;
        if (t2 >= NK) return;
        p = Kb + (size_t)t2 * 2;
        i = t2 & 63;
        s = (t2 >> (6 + 3)) & (S_ - 1);
    }
    float c  = tab[(s * 64 + i) * 2];
    float sn = tab[(s * 64 + i) * 2 + 1];
    ushort2 v = *reinterpret_cast<ushort2*>(p);
    float xr = bf2f(v.x), xi = bf2f(v.y);
    ushort2 o;
    o.x = f2bf(xr * c - xi * sn);
    o.y = f2bf(xr * sn + xi * c);
    *reinterpret_cast<ushort2*>(p) = o;
}

// ---------------- bf16 GEMM, C = A(MxK) * B(NxK)^T, m97 structure ----------------
template <typename OUT_T>
__global__ __launch_bounds__(256) void k_gemm_bt(
    const unsigned short* __restrict__ A,
    const unsigned short* __restrict__ Bm,
    OUT_T* __restrict__ C, int M, int N, int K)
{
    __shared__ __attribute__((aligned(16))) unsigned short As[128 * 64];
    __shared__ __attribute__((aligned(16))) unsigned short Bs[128 * 64];

    const int tid  = threadIdx.x;
    const int lane = tid & 63;
    const int wid  = tid >> 6;
    const int nbn  = N >> 7;
    const int brow = (blockIdx.x / nbn) << 7;
    const int bcol = (blockIdx.x % nbn) << 7;
    const int wr   = (wid >> 1) * 64;
    const int wc   = (wid & 1) * 64;
    const int g    = lane >> 4;
    const int lr   = lane & 15;

    f32x4 acc[4][4] = {};

    for (int k0 = 0; k0 < K; k0 += 64) {
        __syncthreads();
        #pragma unroll
        for (int i2 = 0; i2 < 4; ++i2) {
            int base = (i2 * 4 + wid) * 512;
            int e = base + lane * 8;
            int r = e >> 6, c = e & 63;
            __builtin_amdgcn_global_load_lds(
                (const __attribute__((address_space(1))) void*)(A + (size_t)(brow + r) * K + k0 + c),
                (__attribute__((address_space(3))) void*)(As + base), 16, 0, 0);
            __builtin_amdgcn_global_load_lds(
                (const __attribute__((address_space(1))) void*)(Bm + (size_t)(bcol + r) * K + k0 + c),
                (__attribute__((address_space(3))) void*)(Bs + base), 16, 0, 0);
        }
        __syncthreads();
        #pragma unroll
        for (int kk = 0; kk < 2; ++kk) {
            bf16x8 af[4], bfv[4];
            #pragma unroll
            for (int m = 0; m < 4; ++m)
                af[m] = *reinterpret_cast<const bf16x8*>(&As[(wr + m * 16 + lr) * 64 + kk * 32 + g * 8]);
            #pragma unroll
            for (int n = 0; n < 4; ++n)
                bfv[n] = *reinterpret_cast<const bf16x8*>(&Bs[(wc + n * 16 + lr) * 64 + kk * 32 + g * 8]);
            #pragma unroll
            for (int m = 0; m < 4; ++m)
                #pragma unroll
                for (int n = 0; n < 4; ++n)
                    acc[m][n] = __builtin_amdgcn_mfma_f32_16x16x32_bf16(af[m], bfv[n], acc[m][n], 0, 0, 0);
        }
    }
    #pragma unroll
    for (int m = 0; m < 4; ++m) {
        #pragma unroll
        for (int n = 0; n < 4; ++n) {
            #pragma unroll
            for (int r = 0; r < 4; ++r) {
                int row = brow + wr + m * 16 + g * 4 + r;
                int col = bcol + wc + n * 16 + lr;
                float v = acc[m][n][r];
                if constexpr (std::is_same<OUT_T, float>::value)
                    C[(size_t)row * N + col] = v;
                else
                    C[(size_t)row * N + col] = f2bf(v);
            }
        }
    }
}

// ---------------- flash attention (causal, GQA), v2 ----------------
// 512 blocks x 4 waves; Q-tile 128 (32 rows/wave), KVBLK=64.
// K staged [64][128] XOR-swizzled (16 chunks/row); V staged from pre-transposed
// Vt global as [128][64] XOR-swizzled (8 chunks/row). All staging via
// global_load_lds with pre-swizzled per-lane global source (linear LDS dest).
__global__ __launch_bounds__(256, 2) void k_attn(
    const unsigned short* __restrict__ Q,
    const unsigned short* __restrict__ Kg,
    const unsigned short* __restrict__ Vt,
    unsigned short* __restrict__ O)
{
    __shared__ __attribute__((aligned(16))) unsigned short Ks[64 * 128];
    __shared__ __attribute__((aligned(16))) unsigned short Vs[128 * 64];
    __shared__ __attribute__((aligned(16))) unsigned short Pl[4][32 * 72];

    const int tid  = threadIdx.x;
    const int lane = tid & 63;
    const int wid  = tid >> 6;
    const int g    = lane >> 4;
    const int lr   = lane & 15;

    const int bid    = blockIdx.x;
    const int qt_raw = bid & 15;
    const int h      = (bid >> 4) & 15;
    const int b      = bid >> 8;
    const int qt     = b ? (15 - qt_raw) : qt_raw;   // balance co-resident pairs
    const int hk     = h >> 1;
    const int q0w    = qt * 128 + wid * 32;

    // Q fragments in registers: 2 m-blocks x 4 k-steps
    bf16x8 qf[2][4];
    #pragma unroll
    for (int mb = 0; mb < 2; ++mb)
        #pragma unroll
        for (int c = 0; c < 4; ++c)
            qf[mb][c] = *reinterpret_cast<const bf16x8*>(
                Q + ((size_t)(b * S_ + q0w + mb * 16 + lr) * NH_ + h) * HD_ + c * 32 + g * 8);

    f32x4 o_acc[2][8] = {};
    float m_run[8], l_run[8];
    #pragma unroll
    for (int i = 0; i < 8; ++i) { m_run[i] = -INFINITY; l_run[i] = 0.f; }

    const float C2 = 1.4426950408889634f * 0.08838834764831845f;  // log2e / sqrt(128)
    const int nt = 2 * qt + 2;

    for (int t = 0; t < nt; ++t) {
        const int kv0 = t * 64;
        __syncthreads();   // prev-iter LDS reads done before DMA overwrite
        #pragma unroll
        for (int i4 = 0; i4 < 4; ++i4) {
            const int base = (i4 * 4 + wid) * 512;   // wave-uniform LDS elem base
            const int E = base + lane * 8;
            {   // K tile: row = E>>7 (kv), 16 chunks of 8 elems, chunk ^= row&15
                int row = E >> 7, ch = (E >> 3) & 15;
                int col = ((ch ^ (row & 15)) * 8);
                __builtin_amdgcn_global_load_lds(
                    (const __attribute__((address_space(1))) void*)(
                        Kg + ((size_t)(b * S_ + kv0 + row) * NKV_ + hk) * HD_ + col),
                    (__attribute__((address_space(3))) void*)(Ks + base), 16, 0, 0);
            }
            {   // V tile: row = E>>6 (d), 8 chunks of 8 elems, chunk ^= d&7
                int d = E >> 6, ch = (E >> 3) & 7;
                int kv = ((ch ^ (d & 7)) * 8);
                __builtin_amdgcn_global_load_lds(
                    (const __attribute__((address_space(1))) void*)(
                        Vt + (size_t)(hk * HD_ + d) * (B_ * S_) + b * S_ + kv0 + kv),
                    (__attribute__((address_space(3))) void*)(Vs + base), 16, 0, 0);
            }
        }
        __syncthreads();

        const bool active = kv0 < q0w + 32;
        if (active) {
            // ---- S = Q K^T : 32q x 64kv ----
            f32x4 sv[2][4] = {};
            #pragma unroll
            for (int c = 0; c < 4; ++c)
                #pragma unroll
                for (int kvb = 0; kvb < 4; ++kvb) {
                    bf16x8 kf = *reinterpret_cast<const bf16x8*>(
                        &Ks[(kvb * 16 + lr) * 128 + (((c * 4 + g) ^ lr) * 8)]);
                    #pragma unroll
                    for (int mb = 0; mb < 2; ++mb)
                        sv[mb][kvb] = __builtin_amdgcn_mfma_f32_16x16x32_bf16(
                            qf[mb][c], kf, sv[mb][kvb], 0, 0, 0);
                }

            // ---- causal mask (diagonal tiles only) ----
            if (kv0 + 63 > q0w) {
                #pragma unroll
                for (int mb = 0; mb < 2; ++mb)
                    #pragma unroll
                    for (int kvb = 0; kvb < 4; ++kvb) {
                        int colg = kv0 + kvb * 16 + lr;
                        #pragma unroll
                        for (int r = 0; r < 4; ++r) {
                            int rowg = q0w + mb * 16 + g * 4 + r;
                            if (colg > rowg) sv[mb][kvb][r] = -INFINITY;
                        }
                    }
            }

            // ---- row max (raw units; scale folded into exp2) ----
            float mt[8];
            #pragma unroll
            for (int mb = 0; mb < 2; ++mb)
                #pragma unroll
                for (int r = 0; r < 4; ++r)
                    mt[mb * 4 + r] = fmaxf(fmaxf(sv[mb][0][r], sv[mb][1][r]),
                                           fmaxf(sv[mb][2][r], sv[mb][3][r]));
            #pragma unroll
            for (int i = 0; i < 8; ++i)
                #pragma unroll
                for (int off = 1; off < 16; off <<= 1)
                    mt[i] = fmaxf(mt[i], __shfl_xor(mt[i], off));

            // ---- defer-max rescale (THR = 8 in scaled units = 90.5 raw) ----
            bool need = false;
            #pragma unroll
            for (int i = 0; i < 8; ++i) need |= (mt[i] > m_run[i] + 90.5f);
            if (__any(need)) {
                float al[8];
                #pragma unroll
                for (int i = 0; i < 8; ++i) {
                    float mn = fmaxf(m_run[i], mt[i]);
                    al[i] = exp2f((m_run[i] - mn) * C2);
                    m_run[i] = mn;
                    l_run[i] *= al[i];
                }
                #pragma unroll
                for (int mb = 0; mb < 2; ++mb)
                    #pragma unroll
                    for (int db = 0; db < 8; ++db)
                        #pragma unroll
                        for (int r = 0; r < 4; ++r)
                            o_acc[mb][db][r] *= al[mb * 4 + r];
            }

            // ---- P = exp2((S - m) * C2), bf16 to LDS + row sums ----
            float mb2[8];
            #pragma unroll
            for (int i = 0; i < 8; ++i) mb2[i] = m_run[i] * C2;
            float rs[8] = {0.f, 0.f, 0.f, 0.f, 0.f, 0.f, 0.f, 0.f};
            #pragma unroll
            for (int mb = 0; mb < 2; ++mb)
                #pragma unroll
                for (int kvb = 0; kvb < 4; ++kvb)
                    #pragma unroll
                    for (int r = 0; r < 4; ++r) {
                        float p = exp2f(fmaf(sv[mb][kvb][r], C2, -mb2[mb * 4 + r]));
                        rs[mb * 4 + r] += p;
                        Pl[wid][(mb * 16 + g * 4 + r) * 72 + kvb * 16 + lr] = f2bf(p);
                    }
            #pragma unroll
            for (int i = 0; i < 8; ++i) {
                #pragma unroll
                for (int off = 1; off < 16; off <<= 1)
                    rs[i] += __shfl_xor(rs[i], off);
                l_run[i] += rs[i];
            }

            // ---- O += P V ----
            #pragma unroll
            for (int kk = 0; kk < 2; ++kk) {
                bf16x8 pa[2];
                #pragma unroll
                for (int mb = 0; mb < 2; ++mb)
                    pa[mb] = *reinterpret_cast<const bf16x8*>(
                        &Pl[wid][(mb * 16 + lr) * 72 + kk * 32 + g * 8]);
                #pragma unroll
                for (int db = 0; db < 8; ++db) {
                    bf16x8 vf = *reinterpret_cast<const bf16x8*>(
                        &Vs[(db * 16 + lr) * 64 + (((kk * 4 + g) ^ (lr & 7)) * 8)]);
                    #pragma unroll
                    for (int mb = 0; mb < 2; ++mb)
                        o_acc[mb][db] = __builtin_amdgcn_mfma_f32_16x16x32_bf16(
                            pa[mb], vf, o_acc[mb][db], 0, 0, 0);
                }
            }
        }
    }

    // ---- epilogue: normalize, store bf16 [b,s,h,d] ----
    float inv[8];
    #pragma unroll
    for (int i = 0; i < 8; ++i) inv[i] = 1.f / l_run[i];
    #pragma unroll
    for (int mb = 0; mb < 2; ++mb)
        #pragma unroll
        for (int db = 0; db < 8; ++db)
            #pragma unroll
            for (int r = 0; r < 4; ++r) {
                int rowg = q0w + mb * 16 + g * 4 + r;
                O[((size_t)(b * S_ + rowg) * NH_ + h) * HD_ + db * 16 + lr] =
                    f2bf(o_acc[mb][db][r] * inv[mb * 4 + r]);
            }
}

// ---------------- launcher ----------------
extern "C" void kernel_launch(void* const* d_in, const int* in_sizes, int n_in,
                              void* d_out, int out_size, void* d_ws, size_t ws_size,
                              hipStream_t stream)
{
    const float* x  = (const float*)d_in[0];
    const float* wq = (const float*)d_in[1];
    const float* wk = (const float*)d_in[2];
    const float* wv = (const float*)d_in[3];
    const float* wo = (const float*)d_in[4];
    float* out = (float*)d_out;

    char* ws = (char*)d_ws;
    size_t off = 0;
    auto alloc = [&](size_t bytes) -> void* {
        void* p = ws + off;
        off += (bytes + 255) & ~(size_t)255;
        return p;
    };
    unsigned short* xb  = (unsigned short*)alloc((size_t)B_ * S_ * DIM_ * 2);
    unsigned short* wqb = (unsigned short*)alloc((size_t)DIM_ * DIM_ * 2);
    unsigned short* wkb = (unsigned short*)alloc((size_t)NKV_ * HD_ * DIM_ * 2);
    unsigned short* wvb = (unsigned short*)alloc((size_t)NKV_ * HD_ * DIM_ * 2);
    unsigned short* wob = (unsigned short*)alloc((size_t)DIM_ * DIM_ * 2);
    unsigned short* Qb  = (unsigned short*)alloc((size_t)B_ * S_ * NH_ * HD_ * 2);
    unsigned short* Kb  = (unsigned short*)alloc((size_t)B_ * S_ * NKV_ * HD_ * 2);
    unsigned short* Vtb = (unsigned short*)alloc((size_t)B_ * S_ * NKV_ * HD_ * 2);  // [hk*128+d][b*2048+s]
    unsigned short* Ob  = (unsigned short*)alloc((size_t)B_ * S_ * NH_ * HD_ * 2);
    float* tab = (float*)alloc((size_t)S_ * 64 * 2 * 4);

    const int M = B_ * S_;  // 4096

    // 1) convert inputs to bf16
    k_convert<<<20480, 256, 0, stream>>>(x, wq, wk, wv, wo, xb, wqb, wkb, wvb, wob);
    // 2) RoPE table
    k_rope_table<<<(S_ * 64 + 255) / 256, 256, 0, stream>>>(tab);
    // 3) projections: Q,K normal; V with swapped operands -> transposed output
    k_gemm_bt<unsigned short><<<(M / 128) * (2048 / 128), 256, 0, stream>>>(xb, wqb, Qb, M, 2048, 2048);
    k_gemm_bt<unsigned short><<<(M / 128) * (1024 / 128), 256, 0, stream>>>(xb, wkb, Kb, M, 1024, 2048);
    k_gemm_bt<unsigned short><<<(1024 / 128) * (M / 128), 256, 0, stream>>>(wvb, xb, Vtb, 1024, M, 2048);
    // 4) RoPE on Q and K (in-place; V untouched)
    k_rope<<<(B_ * S_ * NH_ * 64 + B_ * S_ * NKV_ * 64 + 255) / 256, 256, 0, stream>>>(Qb, Kb, tab);
    // 5) attention
    k_attn<<<B_ * NH_ * (S_ / 128), 256, 0, stream>>>(Qb, Kb, Vtb, Ob);
    // 6) output projection -> fp32
    k_gemm_bt<float><<<(M / 128) * (2048 / 128), 256, 0, stream>>>(Ob, wob, out, M, 2048, 2048);

    (void)in_sizes; (void)n_in; (void)out_size; (void)ws_size;
}

// Round 3
// 281.667 us; speedup vs baseline: 1.8892x; 1.1547x over previous
//
#include <hip/hip_runtime.h>
#include <hip/hip_bf16.h>
#include <stdint.h>
#include <type_traits>

typedef __attribute__((ext_vector_type(4))) float   f32x4;
typedef __attribute__((ext_vector_type(8))) __bf16  bf16x8;

#define B_   2
#define S_   2048
#define DIM_ 2048
#define NH_  16
#define NKV_ 8
#define HD_  128

__device__ inline unsigned short f2bf(float f) {
    unsigned u = __float_as_uint(f);
    unsigned r = (u + 0x7fffu + ((u >> 16) & 1u)) >> 16;
    return (unsigned short)r;
}
__device__ inline float bf2f(unsigned short s) {
    return __uint_as_float(((unsigned)s) << 16);
}

// ---------------- fused fp32 -> bf16 convert (x, wq|wk stacked, wv, wo) ----------------
__global__ void k_convert(const float* __restrict__ x,  const float* __restrict__ wq,
                          const float* __restrict__ wk, const float* __restrict__ wv,
                          const float* __restrict__ wo,
                          unsigned short* __restrict__ xb,  unsigned short* __restrict__ wqkb,
                          unsigned short* __restrict__ wvb, unsigned short* __restrict__ wob)
{
    int i = blockIdx.x * blockDim.x + threadIdx.x;  // quad index
    const int NX = 2097152, NWQ = 1048576, NWK = 524288, NWV = 524288, NWO = 1048576;
    const float* src; unsigned short* dst; int j = i;
    if (j < NX) { src = x; dst = xb; }
    else {
        j -= NX;
        if (j < NWQ) { src = wq; dst = wqkb; }
        else {
            j -= NWQ;
            if (j < NWK) { src = wk; dst = wqkb + (size_t)2048 * 2048 / 4 * 4; dst = wqkb + (size_t)2048 * 2048; }
            else {
                j -= NWK;
                if (j < NWV) { src = wv; dst = wvb; }
                else { j -= NWV; if (j >= NWO) return; src = wo; dst = wob; }
            }
        }
    }
    float4 v = reinterpret_cast<const float4*>(src)[j];
    ushort4 o;
    o.x = f2bf(v.x); o.y = f2bf(v.y); o.z = f2bf(v.z); o.w = f2bf(v.w);
    reinterpret_cast<ushort4*>(dst)[j] = o;
}

// ---------------- RoPE cos/sin table: [S][64] float2 ----------------
__global__ void k_rope_table(float* __restrict__ tab)
{
    int t = blockIdx.x * blockDim.x + threadIdx.x;  // s*64 + i
    if (t >= S_ * 64) return;
    int i = t & 63;
    int s = t >> 6;
    float inv = expf(-((float)i / 64.0f) * 9.210340371976184f);  // 10000^(-i/64)
    float ang = (float)s * inv;
    tab[2 * t]     = cosf(ang);
    tab[2 * t + 1] = sinf(ang);
}

// ---------------- fused QKV GEMM, 1024 uniform 128^2 blocks ----------------
// blocks [0,768):  QK = xb(4096x2048) * wqkb(3072x2048)^T -> QKb[4096][3072] bf16, +RoPE
// blocks [768,1024): Vt = wvb(1024x2048) * xb(4096x2048)^T -> Vtb[1024][4096] bf16
__global__ __launch_bounds__(256) void k_gemm_qkv(
    const unsigned short* __restrict__ xb,
    const unsigned short* __restrict__ wqkb,
    const unsigned short* __restrict__ wvb,
    unsigned short* __restrict__ QKb,
    unsigned short* __restrict__ Vtb,
    const float* __restrict__ tab)
{
    __shared__ __attribute__((aligned(16))) unsigned short As[128 * 64];
    __shared__ __attribute__((aligned(16))) unsigned short Bs[128 * 64];

    const int tid  = threadIdx.x;
    const int lane = tid & 63;
    const int wid  = tid >> 6;
    const int g    = lane >> 4;
    const int lr   = lane & 15;
    const int wr   = (wid >> 1) * 64;
    const int wc   = (wid & 1) * 64;

    const bool isQK = blockIdx.x < 768;
    const unsigned short* A;
    const unsigned short* Bm;
    int brow, bcol, ldc;
    if (isQK) {
        A = xb; Bm = wqkb; ldc = 3072;
        brow = (blockIdx.x / 24) << 7;
        bcol = (blockIdx.x % 24) << 7;
    } else {
        int b2 = blockIdx.x - 768;
        A = wvb; Bm = xb; ldc = 4096;
        brow = (b2 >> 5) << 7;
        bcol = (b2 & 31) << 7;
    }

    f32x4 acc[4][4] = {};

    for (int k0 = 0; k0 < 2048; k0 += 64) {
        __syncthreads();
        #pragma unroll
        for (int i2 = 0; i2 < 4; ++i2) {
            int base = (i2 * 4 + wid) * 512;
            int e = base + lane * 8;
            int r = e >> 6, c = e & 63;
            __builtin_amdgcn_global_load_lds(
                (const __attribute__((address_space(1))) void*)(A + (size_t)(brow + r) * 2048 + k0 + c),
                (__attribute__((address_space(3))) void*)(As + base), 16, 0, 0);
            __builtin_amdgcn_global_load_lds(
                (const __attribute__((address_space(1))) void*)(Bm + (size_t)(bcol + r) * 2048 + k0 + c),
                (__attribute__((address_space(3))) void*)(Bs + base), 16, 0, 0);
        }
        __syncthreads();
        #pragma unroll
        for (int kk = 0; kk < 2; ++kk) {
            bf16x8 af[4], bfv[4];
            #pragma unroll
            for (int m = 0; m < 4; ++m)
                af[m] = *reinterpret_cast<const bf16x8*>(&As[(wr + m * 16 + lr) * 64 + kk * 32 + g * 8]);
            #pragma unroll
            for (int n = 0; n < 4; ++n)
                bfv[n] = *reinterpret_cast<const bf16x8*>(&Bs[(wc + n * 16 + lr) * 64 + kk * 32 + g * 8]);
            #pragma unroll
            for (int m = 0; m < 4; ++m)
                #pragma unroll
                for (int n = 0; n < 4; ++n)
                    acc[m][n] = __builtin_amdgcn_mfma_f32_16x16x32_bf16(af[m], bfv[n], acc[m][n], 0, 0, 0);
        }
    }

    if (isQK) {
        // epilogue with fused RoPE: pairs (even,odd) head-dim are adjacent lanes
        #pragma unroll
        for (int m = 0; m < 4; ++m) {
            #pragma unroll
            for (int n = 0; n < 4; ++n) {
                int col  = bcol + wc + n * 16 + lr;
                int ci   = (col & 127) >> 1;
                int row0 = brow + wr + m * 16 + g * 4;
                #pragma unroll
                for (int r = 0; r < 4; ++r) {
                    int row = row0 + r;
                    int s   = row & (S_ - 1);
                    float2 cs = *reinterpret_cast<const float2*>(&tab[(s * 64 + ci) * 2]);
                    float v = acc[m][n][r];
                    float o = __shfl_xor(v, 1);
                    // even lane: v=xr, o=xi -> xr*c - xi*s ; odd lane: v=xi, o=xr -> xr*s + xi*c
                    float res = (lane & 1) ? fmaf(o, cs.y, v * cs.x)
                                           : fmaf(v, cs.x, -(o * cs.y));
                    QKb[(size_t)row * 3072 + col] = f2bf(res);
                }
            }
        }
    } else {
        #pragma unroll
        for (int m = 0; m < 4; ++m)
            #pragma unroll
            for (int n = 0; n < 4; ++n)
                #pragma unroll
                for (int r = 0; r < 4; ++r) {
                    int row = brow + wr + m * 16 + g * 4 + r;
                    int col = bcol + wc + n * 16 + lr;
                    Vtb[(size_t)row * 4096 + col] = f2bf(acc[m][n][r]);
                }
    }
}

// ---------------- generic bf16 GEMM C = A * B^T (float out), m97 structure ----------------
__global__ __launch_bounds__(256) void k_gemm_bt_f32(
    const unsigned short* __restrict__ A,
    const unsigned short* __restrict__ Bm,
    float* __restrict__ C, int M, int N, int K)
{
    __shared__ __attribute__((aligned(16))) unsigned short As[128 * 64];
    __shared__ __attribute__((aligned(16))) unsigned short Bs[128 * 64];

    const int tid  = threadIdx.x;
    const int lane = tid & 63;
    const int wid  = tid >> 6;
    const int nbn  = N >> 7;
    const int brow = (blockIdx.x / nbn) << 7;
    const int bcol = (blockIdx.x % nbn) << 7;
    const int wr   = (wid >> 1) * 64;
    const int wc   = (wid & 1) * 64;
    const int g    = lane >> 4;
    const int lr   = lane & 15;

    f32x4 acc[4][4] = {};

    for (int k0 = 0; k0 < K; k0 += 64) {
        __syncthreads();
        #pragma unroll
        for (int i2 = 0; i2 < 4; ++i2) {
            int base = (i2 * 4 + wid) * 512;
            int e = base + lane * 8;
            int r = e >> 6, c = e & 63;
            __builtin_amdgcn_global_load_lds(
                (const __attribute__((address_space(1))) void*)(A + (size_t)(brow + r) * K + k0 + c),
                (__attribute__((address_space(3))) void*)(As + base), 16, 0, 0);
            __builtin_amdgcn_global_load_lds(
                (const __attribute__((address_space(1))) void*)(Bm + (size_t)(bcol + r) * K + k0 + c),
                (__attribute__((address_space(3))) void*)(Bs + base), 16, 0, 0);
        }
        __syncthreads();
        #pragma unroll
        for (int kk = 0; kk < 2; ++kk) {
            bf16x8 af[4], bfv[4];
            #pragma unroll
            for (int m = 0; m < 4; ++m)
                af[m] = *reinterpret_cast<const bf16x8*>(&As[(wr + m * 16 + lr) * 64 + kk * 32 + g * 8]);
            #pragma unroll
            for (int n = 0; n < 4; ++n)
                bfv[n] = *reinterpret_cast<const bf16x8*>(&Bs[(wc + n * 16 + lr) * 64 + kk * 32 + g * 8]);
            #pragma unroll
            for (int m = 0; m < 4; ++m)
                #pragma unroll
                for (int n = 0; n < 4; ++n)
                    acc[m][n] = __builtin_amdgcn_mfma_f32_16x16x32_bf16(af[m], bfv[n], acc[m][n], 0, 0, 0);
        }
    }
    #pragma unroll
    for (int m = 0; m < 4; ++m)
        #pragma unroll
        for (int n = 0; n < 4; ++n)
            #pragma unroll
            for (int r = 0; r < 4; ++r) {
                int row = brow + wr + m * 16 + g * 4 + r;
                int col = bcol + wc + n * 16 + lr;
                C[(size_t)row * N + col] = acc[m][n][r];
            }
}

// ---------------- flash attention (causal, GQA) ----------------
// 512 blocks x 4 waves; Q-tile 128 (32 rows/wave), KVBLK=64.
// Q,K from combined QKb [4096][3072]; V from pre-transposed Vtb [1024][4096].
__global__ __launch_bounds__(256, 2) void k_attn(
    const unsigned short* __restrict__ QK,
    const unsigned short* __restrict__ Vt,
    unsigned short* __restrict__ O)
{
    __shared__ __attribute__((aligned(16))) unsigned short Ks[64 * 128];
    __shared__ __attribute__((aligned(16))) unsigned short Vs[128 * 64];
    __shared__ __attribute__((aligned(16))) unsigned short Pl[4][32 * 72];

    const int tid  = threadIdx.x;
    const int lane = tid & 63;
    const int wid  = tid >> 6;
    const int g    = lane >> 4;
    const int lr   = lane & 15;

    const int bid    = blockIdx.x;
    const int qt_raw = bid & 15;
    const int h      = (bid >> 4) & 15;
    const int b      = bid >> 8;
    const int qt     = b ? (15 - qt_raw) : qt_raw;
    const int hk     = h >> 1;
    const int q0w    = qt * 128 + wid * 32;

    bf16x8 qf[2][4];
    #pragma unroll
    for (int mb = 0; mb < 2; ++mb)
        #pragma unroll
        for (int c = 0; c < 4; ++c)
            qf[mb][c] = *reinterpret_cast<const bf16x8*>(
                QK + (size_t)(b * S_ + q0w + mb * 16 + lr) * 3072 + h * HD_ + c * 32 + g * 8);

    f32x4 o_acc[2][8] = {};
    float m_run[8], l_run[8];
    #pragma unroll
    for (int i = 0; i < 8; ++i) { m_run[i] = -INFINITY; l_run[i] = 0.f; }

    const float C2 = 1.4426950408889634f * 0.08838834764831845f;
    const int nt = 2 * qt + 2;

    for (int t = 0; t < nt; ++t) {
        const int kv0 = t * 64;
        __syncthreads();
        #pragma unroll
        for (int i4 = 0; i4 < 4; ++i4) {
            const int base = (i4 * 4 + wid) * 512;
            const int E = base + lane * 8;
            {   // K tile from QKb (+2048 col offset)
                int row = E >> 7, ch = (E >> 3) & 15;
                int col = ((ch ^ (row & 15)) * 8);
                __builtin_amdgcn_global_load_lds(
                    (const __attribute__((address_space(1))) void*)(
                        QK + (size_t)(b * S_ + kv0 + row) * 3072 + 2048 + hk * HD_ + col),
                    (__attribute__((address_space(3))) void*)(Ks + base), 16, 0, 0);
            }
            {   // V tile from Vtb
                int d = E >> 6, ch = (E >> 3) & 7;
                int kv = ((ch ^ (d & 7)) * 8);
                __builtin_amdgcn_global_load_lds(
                    (const __attribute__((address_space(1))) void*)(
                        Vt + (size_t)(hk * HD_ + d) * (B_ * S_) + b * S_ + kv0 + kv),
                    (__attribute__((address_space(3))) void*)(Vs + base), 16, 0, 0);
            }
        }
        __syncthreads();

        const bool active = kv0 < q0w + 32;
        if (active) {
            f32x4 sv[2][4] = {};
            #pragma unroll
            for (int c = 0; c < 4; ++c)
                #pragma unroll
                for (int kvb = 0; kvb < 4; ++kvb) {
                    bf16x8 kf = *reinterpret_cast<const bf16x8*>(
                        &Ks[(kvb * 16 + lr) * 128 + (((c * 4 + g) ^ lr) * 8)]);
                    #pragma unroll
                    for (int mb = 0; mb < 2; ++mb)
                        sv[mb][kvb] = __builtin_amdgcn_mfma_f32_16x16x32_bf16(
                            qf[mb][c], kf, sv[mb][kvb], 0, 0, 0);
                }

            if (kv0 + 63 > q0w) {
                #pragma unroll
                for (int mb = 0; mb < 2; ++mb)
                    #pragma unroll
                    for (int kvb = 0; kvb < 4; ++kvb) {
                        int colg = kv0 + kvb * 16 + lr;
                        #pragma unroll
                        for (int r = 0; r < 4; ++r) {
                            int rowg = q0w + mb * 16 + g * 4 + r;
                            if (colg > rowg) sv[mb][kvb][r] = -INFINITY;
                        }
                    }
            }

            float mt[8];
            #pragma unroll
            for (int mb = 0; mb < 2; ++mb)
                #pragma unroll
                for (int r = 0; r < 4; ++r)
                    mt[mb * 4 + r] = fmaxf(fmaxf(sv[mb][0][r], sv[mb][1][r]),
                                           fmaxf(sv[mb][2][r], sv[mb][3][r]));
            #pragma unroll
            for (int i = 0; i < 8; ++i)
                #pragma unroll
                for (int off = 1; off < 16; off <<= 1)
                    mt[i] = fmaxf(mt[i], __shfl_xor(mt[i], off));

            bool need = false;
            #pragma unroll
            for (int i = 0; i < 8; ++i) need |= (mt[i] > m_run[i] + 90.5f);
            if (__any(need)) {
                float al[8];
                #pragma unroll
                for (int i = 0; i < 8; ++i) {
                    float mn = fmaxf(m_run[i], mt[i]);
                    al[i] = exp2f((m_run[i] - mn) * C2);
                    m_run[i] = mn;
                    l_run[i] *= al[i];
                }
                #pragma unroll
                for (int mb = 0; mb < 2; ++mb)
                    #pragma unroll
                    for (int db = 0; db < 8; ++db)
                        #pragma unroll
                        for (int r = 0; r < 4; ++r)
                            o_acc[mb][db][r] *= al[mb * 4 + r];
            }

            float mb2[8];
            #pragma unroll
            for (int i = 0; i < 8; ++i) mb2[i] = m_run[i] * C2;
            float rs[8] = {0.f, 0.f, 0.f, 0.f, 0.f, 0.f, 0.f, 0.f};
            #pragma unroll
            for (int mb = 0; mb < 2; ++mb)
                #pragma unroll
                for (int kvb = 0; kvb < 4; ++kvb)
                    #pragma unroll
                    for (int r = 0; r < 4; ++r) {
                        float p = exp2f(fmaf(sv[mb][kvb][r], C2, -mb2[mb * 4 + r]));
                        rs[mb * 4 + r] += p;
                        Pl[wid][(mb * 16 + g * 4 + r) * 72 + kvb * 16 + lr] = f2bf(p);
                    }
            #pragma unroll
            for (int i = 0; i < 8; ++i) {
                #pragma unroll
                for (int off = 1; off < 16; off <<= 1)
                    rs[i] += __shfl_xor(rs[i], off);
                l_run[i] += rs[i];
            }

            #pragma unroll
            for (int kk = 0; kk < 2; ++kk) {
                bf16x8 pa[2];
                #pragma unroll
                for (int mb = 0; mb < 2; ++mb)
                    pa[mb] = *reinterpret_cast<const bf16x8*>(
                        &Pl[wid][(mb * 16 + lr) * 72 + kk * 32 + g * 8]);
                #pragma unroll
                for (int db = 0; db < 8; ++db) {
                    bf16x8 vf = *reinterpret_cast<const bf16x8*>(
                        &Vs[(db * 16 + lr) * 64 + (((kk * 4 + g) ^ (lr & 7)) * 8)]);
                    #pragma unroll
                    for (int mb = 0; mb < 2; ++mb)
                        o_acc[mb][db] = __builtin_amdgcn_mfma_f32_16x16x32_bf16(
                            pa[mb], vf, o_acc[mb][db], 0, 0, 0);
                }
            }
        }
    }

    float inv[8];
    #pragma unroll
    for (int i = 0; i < 8; ++i) inv[i] = 1.f / l_run[i];
    #pragma unroll
    for (int mb = 0; mb < 2; ++mb)
        #pragma unroll
        for (int db = 0; db < 8; ++db)
            #pragma unroll
            for (int r = 0; r < 4; ++r) {
                int rowg = q0w + mb * 16 + g * 4 + r;
                O[((size_t)(b * S_ + rowg) * NH_ + h) * HD_ + db * 16 + lr] =
                    f2bf(o_acc[mb][db][r] * inv[mb * 4 + r]);
            }
}

// ---------------- launcher ----------------
extern "C" void kernel_launch(void* const* d_in, const int* in_sizes, int n_in,
                              void* d_out, int out_size, void* d_ws, size_t ws_size,
                              hipStream_t stream)
{
    const float* x  = (const float*)d_in[0];
    const float* wq = (const float*)d_in[1];
    const float* wk = (const float*)d_in[2];
    const float* wv = (const float*)d_in[3];
    const float* wo = (const float*)d_in[4];
    float* out = (float*)d_out;

    char* ws = (char*)d_ws;
    size_t off = 0;
    auto alloc = [&](size_t bytes) -> void* {
        void* p = ws + off;
        off += (bytes + 255) & ~(size_t)255;
        return p;
    };
    unsigned short* xb   = (unsigned short*)alloc((size_t)B_ * S_ * DIM_ * 2);
    unsigned short* wqkb = (unsigned short*)alloc((size_t)3072 * 2048 * 2);
    unsigned short* wvb  = (unsigned short*)alloc((size_t)1024 * 2048 * 2);
    unsigned short* wob  = (unsigned short*)alloc((size_t)DIM_ * DIM_ * 2);
    unsigned short* QKb  = (unsigned short*)alloc((size_t)B_ * S_ * 3072 * 2);
    unsigned short* Vtb  = (unsigned short*)alloc((size_t)1024 * B_ * S_ * 2);
    unsigned short* Ob   = (unsigned short*)alloc((size_t)B_ * S_ * NH_ * HD_ * 2);
    float* tab = (float*)alloc((size_t)S_ * 64 * 2 * 4);

    const int M = B_ * S_;  // 4096

    k_convert<<<20480, 256, 0, stream>>>(x, wq, wk, wv, wo, xb, wqkb, wvb, wob);
    k_rope_table<<<(S_ * 64 + 255) / 256, 256, 0, stream>>>(tab);
    k_gemm_qkv<<<1024, 256, 0, stream>>>(xb, wqkb, wvb, QKb, Vtb, tab);
    k_attn<<<B_ * NH_ * (S_ / 128), 256, 0, stream>>>(QKb, Vtb, Ob);
    k_gemm_bt_f32<<<(M / 128) * (2048 / 128), 256, 0, stream>>>(Ob, wob, out, M, 2048, 2048);

    (void)in_sizes; (void)n_in; (void)out_size; (void)ws_size;
}

// Round 4
// 262.360 us; speedup vs baseline: 2.0282x; 1.0736x over previous
//
#include <hip/hip_runtime.h>
#include <hip/hip_bf16.h>
#include <stdint.h>
#include <type_traits>

typedef __attribute__((ext_vector_type(4))) float   f32x4;
typedef __attribute__((ext_vector_type(8))) __bf16  bf16x8;
typedef __attribute__((ext_vector_type(4))) unsigned int u32x4;

#define B_   2
#define S_   2048
#define DIM_ 2048
#define NH_  16
#define NKV_ 8
#define HD_  128

__device__ inline unsigned short f2bf(float f) {
    unsigned u = __float_as_uint(f);
    unsigned r = (u + 0x7fffu + ((u >> 16) & 1u)) >> 16;
    return (unsigned short)r;
}
__device__ inline float bf2f(unsigned short s) {
    return __uint_as_float(((unsigned)s) << 16);
}

// ---------------- fused fp32 -> bf16 convert (x, wq|wk stacked, wv, wo) ----------------
__global__ void k_convert(const float* __restrict__ x,  const float* __restrict__ wq,
                          const float* __restrict__ wk, const float* __restrict__ wv,
                          const float* __restrict__ wo,
                          unsigned short* __restrict__ xb,  unsigned short* __restrict__ wqkb,
                          unsigned short* __restrict__ wvb, unsigned short* __restrict__ wob)
{
    int i = blockIdx.x * blockDim.x + threadIdx.x;  // quad index
    const int NX = 2097152, NWQ = 1048576, NWK = 524288, NWV = 524288, NWO = 1048576;
    const float* src; unsigned short* dst; int j = i;
    if (j < NX) { src = x; dst = xb; }
    else {
        j -= NX;
        if (j < NWQ) { src = wq; dst = wqkb; }
        else {
            j -= NWQ;
            if (j < NWK) { src = wk; dst = wqkb + (size_t)2048 * 2048; }
            else {
                j -= NWK;
                if (j < NWV) { src = wv; dst = wvb; }
                else { j -= NWV; if (j >= NWO) return; src = wo; dst = wob; }
            }
        }
    }
    float4 v = reinterpret_cast<const float4*>(src)[j];
    ushort4 o;
    o.x = f2bf(v.x); o.y = f2bf(v.y); o.z = f2bf(v.z); o.w = f2bf(v.w);
    reinterpret_cast<ushort4*>(dst)[j] = o;
}

// ---------------- RoPE cos/sin table: [S][64] float2 ----------------
__global__ void k_rope_table(float* __restrict__ tab)
{
    int t = blockIdx.x * blockDim.x + threadIdx.x;  // s*64 + i
    if (t >= S_ * 64) return;
    int i = t & 63;
    int s = t >> 6;
    float inv = expf(-((float)i / 64.0f) * 9.210340371976184f);  // 10000^(-i/64)
    float ang = (float)s * inv;
    tab[2 * t]     = cosf(ang);
    tab[2 * t + 1] = sinf(ang);
}

// ---------------- fused QKV GEMM, 1024 uniform 128^2 blocks ----------------
// blocks [0,768):  QK = xb(4096x2048) * wqkb(3072x2048)^T -> QKb[4096][3072] bf16, +RoPE
// blocks [768,1024): Vt = wvb(1024x2048) * xb(4096x2048)^T -> Vtb[1024][4096] bf16
__global__ __launch_bounds__(256) void k_gemm_qkv(
    const unsigned short* __restrict__ xb,
    const unsigned short* __restrict__ wqkb,
    const unsigned short* __restrict__ wvb,
    unsigned short* __restrict__ QKb,
    unsigned short* __restrict__ Vtb,
    const float* __restrict__ tab)
{
    __shared__ __attribute__((aligned(16))) unsigned short As[128 * 64];
    __shared__ __attribute__((aligned(16))) unsigned short Bs[128 * 64];

    const int tid  = threadIdx.x;
    const int lane = tid & 63;
    const int wid  = tid >> 6;
    const int g    = lane >> 4;
    const int lr   = lane & 15;
    const int wr   = (wid >> 1) * 64;
    const int wc   = (wid & 1) * 64;

    const bool isQK = blockIdx.x < 768;
    const unsigned short* A;
    const unsigned short* Bm;
    int brow, bcol;
    if (isQK) {
        A = xb; Bm = wqkb;
        brow = (blockIdx.x / 24) << 7;
        bcol = (blockIdx.x % 24) << 7;
    } else {
        int b2 = blockIdx.x - 768;
        A = wvb; Bm = xb;
        brow = (b2 >> 5) << 7;
        bcol = (b2 & 31) << 7;
    }

    f32x4 acc[4][4] = {};

    for (int k0 = 0; k0 < 2048; k0 += 64) {
        __syncthreads();
        #pragma unroll
        for (int i2 = 0; i2 < 4; ++i2) {
            int base = (i2 * 4 + wid) * 512;
            int e = base + lane * 8;
            int r = e >> 6, c = e & 63;
            __builtin_amdgcn_global_load_lds(
                (const __attribute__((address_space(1))) void*)(A + (size_t)(brow + r) * 2048 + k0 + c),
                (__attribute__((address_space(3))) void*)(As + base), 16, 0, 0);
            __builtin_amdgcn_global_load_lds(
                (const __attribute__((address_space(1))) void*)(Bm + (size_t)(bcol + r) * 2048 + k0 + c),
                (__attribute__((address_space(3))) void*)(Bs + base), 16, 0, 0);
        }
        __syncthreads();
        #pragma unroll
        for (int kk = 0; kk < 2; ++kk) {
            bf16x8 af[4], bfv[4];
            #pragma unroll
            for (int m = 0; m < 4; ++m)
                af[m] = *reinterpret_cast<const bf16x8*>(&As[(wr + m * 16 + lr) * 64 + kk * 32 + g * 8]);
            #pragma unroll
            for (int n = 0; n < 4; ++n)
                bfv[n] = *reinterpret_cast<const bf16x8*>(&Bs[(wc + n * 16 + lr) * 64 + kk * 32 + g * 8]);
            #pragma unroll
            for (int m = 0; m < 4; ++m)
                #pragma unroll
                for (int n = 0; n < 4; ++n)
                    acc[m][n] = __builtin_amdgcn_mfma_f32_16x16x32_bf16(af[m], bfv[n], acc[m][n], 0, 0, 0);
        }
    }

    if (isQK) {
        // epilogue with fused RoPE: (even,odd) head-dim pairs are adjacent lanes
        #pragma unroll
        for (int m = 0; m < 4; ++m) {
            #pragma unroll
            for (int n = 0; n < 4; ++n) {
                int col  = bcol + wc + n * 16 + lr;
                int ci   = (col & 127) >> 1;
                int row0 = brow + wr + m * 16 + g * 4;
                #pragma unroll
                for (int r = 0; r < 4; ++r) {
                    int row = row0 + r;
                    int s   = row & (S_ - 1);
                    float2 cs = *reinterpret_cast<const float2*>(&tab[(s * 64 + ci) * 2]);
                    float v = acc[m][n][r];
                    float o = __shfl_xor(v, 1);
                    float res = (lane & 1) ? fmaf(o, cs.y, v * cs.x)
                                           : fmaf(v, cs.x, -(o * cs.y));
                    QKb[(size_t)row * 3072 + col] = f2bf(res);
                }
            }
        }
    } else {
        #pragma unroll
        for (int m = 0; m < 4; ++m)
            #pragma unroll
            for (int n = 0; n < 4; ++n)
                #pragma unroll
                for (int r = 0; r < 4; ++r) {
                    int row = brow + wr + m * 16 + g * 4 + r;
                    int col = bcol + wc + n * 16 + lr;
                    Vtb[(size_t)row * 4096 + col] = f2bf(acc[m][n][r]);
                }
    }
}

// ---------------- generic bf16 GEMM C = A * B^T (float out), m97 structure ----------------
__global__ __launch_bounds__(256) void k_gemm_bt_f32(
    const unsigned short* __restrict__ A,
    const unsigned short* __restrict__ Bm,
    float* __restrict__ C, int M, int N, int K)
{
    __shared__ __attribute__((aligned(16))) unsigned short As[128 * 64];
    __shared__ __attribute__((aligned(16))) unsigned short Bs[128 * 64];

    const int tid  = threadIdx.x;
    const int lane = tid & 63;
    const int wid  = tid >> 6;
    const int nbn  = N >> 7;
    const int brow = (blockIdx.x / nbn) << 7;
    const int bcol = (blockIdx.x % nbn) << 7;
    const int wr   = (wid >> 1) * 64;
    const int wc   = (wid & 1) * 64;
    const int g    = lane >> 4;
    const int lr   = lane & 15;

    f32x4 acc[4][4] = {};

    for (int k0 = 0; k0 < K; k0 += 64) {
        __syncthreads();
        #pragma unroll
        for (int i2 = 0; i2 < 4; ++i2) {
            int base = (i2 * 4 + wid) * 512;
            int e = base + lane * 8;
            int r = e >> 6, c = e & 63;
            __builtin_amdgcn_global_load_lds(
                (const __attribute__((address_space(1))) void*)(A + (size_t)(brow + r) * K + k0 + c),
                (__attribute__((address_space(3))) void*)(As + base), 16, 0, 0);
            __builtin_amdgcn_global_load_lds(
                (const __attribute__((address_space(1))) void*)(Bm + (size_t)(bcol + r) * K + k0 + c),
                (__attribute__((address_space(3))) void*)(Bs + base), 16, 0, 0);
        }
        __syncthreads();
        #pragma unroll
        for (int kk = 0; kk < 2; ++kk) {
            bf16x8 af[4], bfv[4];
            #pragma unroll
            for (int m = 0; m < 4; ++m)
                af[m] = *reinterpret_cast<const bf16x8*>(&As[(wr + m * 16 + lr) * 64 + kk * 32 + g * 8]);
            #pragma unroll
            for (int n = 0; n < 4; ++n)
                bfv[n] = *reinterpret_cast<const bf16x8*>(&Bs[(wc + n * 16 + lr) * 64 + kk * 32 + g * 8]);
            #pragma unroll
            for (int m = 0; m < 4; ++m)
                #pragma unroll
                for (int n = 0; n < 4; ++n)
                    acc[m][n] = __builtin_amdgcn_mfma_f32_16x16x32_bf16(af[m], bfv[n], acc[m][n], 0, 0, 0);
        }
    }
    #pragma unroll
    for (int m = 0; m < 4; ++m)
        #pragma unroll
        for (int n = 0; n < 4; ++n)
            #pragma unroll
            for (int r = 0; r < 4; ++r) {
                int row = brow + wr + m * 16 + g * 4 + r;
                int col = bcol + wc + n * 16 + lr;
                C[(size_t)row * N + col] = acc[m][n][r];
            }
}

// ---------------- flash attention (causal, GQA), v3: swapped QK^T + in-reg softmax ----------------
// 512 blocks x 4 waves; Q-tile 128 (32 rows/wave), KVBLK=64.
// S^T = mfma(K,Q): lane holds q-col = lane&15, kv rows = (lane>>4)*4+r (+16*kvb).
// Softmax stats per lane: 2 scalars (one per 16-row q sub-block). P transposed to
// PV B-fragment layout fully in-register via ds_bpermute shuffles. No P LDS buffer.
// PV computes O^T = mfma(V^T-frag, P^T-frag).
__global__ __launch_bounds__(256, 2) void k_attn(
    const unsigned short* __restrict__ QK,
    const unsigned short* __restrict__ Vt,
    unsigned short* __restrict__ O)
{
    __shared__ __attribute__((aligned(16))) unsigned short Ks[64 * 128];
    __shared__ __attribute__((aligned(16))) unsigned short Vs[128 * 64];

    const int tid  = threadIdx.x;
    const int lane = tid & 63;
    const int wid  = tid >> 6;
    const int g    = lane >> 4;
    const int lr   = lane & 15;

    const int bid    = blockIdx.x;
    const int qt_raw = bid & 15;
    const int h      = (bid >> 4) & 15;
    const int b      = bid >> 8;
    const int qt     = b ? (15 - qt_raw) : qt_raw;   // balance co-resident pairs
    const int hk     = h >> 1;
    const int q0w    = qt * 128 + wid * 32;

    // Q fragments (B-operand of swapped QK^T): same addressing as A-frag
    bf16x8 qf[2][4];
    #pragma unroll
    for (int qb = 0; qb < 2; ++qb)
        #pragma unroll
        for (int c = 0; c < 4; ++c)
            qf[qb][c] = *reinterpret_cast<const bf16x8*>(
                QK + (size_t)(b * S_ + q0w + qb * 16 + lr) * 3072 + h * HD_ + c * 32 + g * 8);

    f32x4 o_acc[2][8] = {};                  // [qb][db]: O^T frag, q=lr, d=db*16+g*4+r
    float m_run[2] = {-INFINITY, -INFINITY};
    float l_run[2] = {0.f, 0.f};

    const float C2 = 1.4426950408889634f * 0.08838834764831845f;  // log2e/sqrt(128)
    const int nt = 2 * qt + 2;
    const int srcb = (g & 1) * 32 + lr;      // exchange source lane (lo half)
    const bool hig = g >> 1;                  // selects kvb parity

    for (int t = 0; t < nt; ++t) {
        const int kv0 = t * 64;
        __syncthreads();   // prev-iter LDS reads done before DMA overwrite
        #pragma unroll
        for (int i4 = 0; i4 < 4; ++i4) {
            const int base = (i4 * 4 + wid) * 512;
            const int E = base + lane * 8;
            {   // K tile from QKb (+2048 col offset), 16-chunk XOR swizzle
                int row = E >> 7, ch = (E >> 3) & 15;
                int col = ((ch ^ (row & 15)) * 8);
                __builtin_amdgcn_global_load_lds(
                    (const __attribute__((address_space(1))) void*)(
                        QK + (size_t)(b * S_ + kv0 + row) * 3072 + 2048 + hk * HD_ + col),
                    (__attribute__((address_space(3))) void*)(Ks + base), 16, 0, 0);
            }
            {   // V tile from Vtb [d][kv], 8-chunk XOR swizzle
                int d = E >> 6, ch = (E >> 3) & 7;
                int kv = ((ch ^ (d & 7)) * 8);
                __builtin_amdgcn_global_load_lds(
                    (const __attribute__((address_space(1))) void*)(
                        Vt + (size_t)(hk * HD_ + d) * (B_ * S_) + b * S_ + kv0 + kv),
                    (__attribute__((address_space(3))) void*)(Vs + base), 16, 0, 0);
            }
        }
        __syncthreads();

        const bool active = kv0 < q0w + 32;
        if (active) {
            // ---- S^T = K Q^T : sv[qb][kvb][r] = S[kv0+kvb*16+g*4+r][q0w+qb*16+lr]
            f32x4 sv[2][4] = {};
            #pragma unroll
            for (int c = 0; c < 4; ++c)
                #pragma unroll
                for (int kvb = 0; kvb < 4; ++kvb) {
                    bf16x8 kf = *reinterpret_cast<const bf16x8*>(
                        &Ks[(kvb * 16 + lr) * 128 + (((c * 4 + g) ^ lr) * 8)]);
                    #pragma unroll
                    for (int qb = 0; qb < 2; ++qb)
                        sv[qb][kvb] = __builtin_amdgcn_mfma_f32_16x16x32_bf16(
                            kf, qf[qb][c], sv[qb][kvb], 0, 0, 0);
                }

            // ---- causal mask (diagonal tiles only): kv > q -> -inf
            if (kv0 + 63 > q0w) {
                #pragma unroll
                for (int qb = 0; qb < 2; ++qb) {
                    int qg = q0w + qb * 16 + lr;
                    #pragma unroll
                    for (int kvb = 0; kvb < 4; ++kvb) {
                        int kvg0 = kv0 + kvb * 16 + g * 4;
                        #pragma unroll
                        for (int r = 0; r < 4; ++r)
                            if (kvg0 + r > qg) sv[qb][kvb][r] = -INFINITY;
                    }
                }
            }

            // ---- row max: 15 lane-local + 2 shuffles
            float mt[2];
            #pragma unroll
            for (int qb = 0; qb < 2; ++qb) {
                float a = fmaxf(fmaxf(sv[qb][0][0], sv[qb][0][1]), fmaxf(sv[qb][0][2], sv[qb][0][3]));
                float c2m = fmaxf(fmaxf(sv[qb][1][0], sv[qb][1][1]), fmaxf(sv[qb][1][2], sv[qb][1][3]));
                float c3 = fmaxf(fmaxf(sv[qb][2][0], sv[qb][2][1]), fmaxf(sv[qb][2][2], sv[qb][2][3]));
                float c4 = fmaxf(fmaxf(sv[qb][3][0], sv[qb][3][1]), fmaxf(sv[qb][3][2], sv[qb][3][3]));
                float m0 = fmaxf(fmaxf(a, c2m), fmaxf(c3, c4));
                m0 = fmaxf(m0, __shfl_xor(m0, 16));
                m0 = fmaxf(m0, __shfl_xor(m0, 32));
                mt[qb] = m0;
            }

            // ---- defer-max rescale (THR = 8 scaled = 90.5 raw)
            bool need = (mt[0] > m_run[0] + 90.5f) | (mt[1] > m_run[1] + 90.5f);
            if (__any(need)) {
                #pragma unroll
                for (int qb = 0; qb < 2; ++qb) {
                    float mn = fmaxf(m_run[qb], mt[qb]);
                    float al = exp2f((m_run[qb] - mn) * C2);
                    m_run[qb] = mn;
                    l_run[qb] *= al;
                    #pragma unroll
                    for (int db = 0; db < 8; ++db)
                        #pragma unroll
                        for (int r = 0; r < 4; ++r)
                            o_acc[qb][db][r] *= al;
                }
            }

            // ---- P = exp2((S-m)*C2); pack bf16 pairs; row sums
            unsigned pk[2][4][2];
            #pragma unroll
            for (int qb = 0; qb < 2; ++qb) {
                float mb2 = m_run[qb] * C2;
                float rs = 0.f;
                #pragma unroll
                for (int kvb = 0; kvb < 4; ++kvb) {
                    float p0 = exp2f(fmaf(sv[qb][kvb][0], C2, -mb2));
                    float p1 = exp2f(fmaf(sv[qb][kvb][1], C2, -mb2));
                    float p2 = exp2f(fmaf(sv[qb][kvb][2], C2, -mb2));
                    float p3 = exp2f(fmaf(sv[qb][kvb][3], C2, -mb2));
                    rs += (p0 + p1) + (p2 + p3);
                    pk[qb][kvb][0] = (unsigned)f2bf(p0) | ((unsigned)f2bf(p1) << 16);
                    pk[qb][kvb][1] = (unsigned)f2bf(p2) | ((unsigned)f2bf(p3) << 16);
                }
                rs += __shfl_xor(rs, 16);
                rs += __shfl_xor(rs, 32);
                l_run[qb] += rs;
            }

            // ---- in-register transpose to PV B-frag: pb[qb][kk], k-elem j -> kv=kk*32+8g+j
            // j0..3 from lane (2(g&1))*16+lr of kvb=2kk+(g>>1); j4..7 from +16 lane.
            #pragma unroll
            for (int kk = 0; kk < 2; ++kk) {
                u32x4 w[2];
                #pragma unroll
                for (int qb = 0; qb < 2; ++qb) {
                    unsigned a0 = (unsigned)__shfl((int)pk[qb][2 * kk][0], srcb);
                    unsigned a1 = (unsigned)__shfl((int)pk[qb][2 * kk][1], srcb);
                    unsigned a2 = (unsigned)__shfl((int)pk[qb][2 * kk][0], srcb + 16);
                    unsigned a3 = (unsigned)__shfl((int)pk[qb][2 * kk][1], srcb + 16);
                    unsigned b0 = (unsigned)__shfl((int)pk[qb][2 * kk + 1][0], srcb);
                    unsigned b1 = (unsigned)__shfl((int)pk[qb][2 * kk + 1][1], srcb);
                    unsigned b2 = (unsigned)__shfl((int)pk[qb][2 * kk + 1][0], srcb + 16);
                    unsigned b3 = (unsigned)__shfl((int)pk[qb][2 * kk + 1][1], srcb + 16);
                    w[qb][0] = hig ? b0 : a0;
                    w[qb][1] = hig ? b1 : a1;
                    w[qb][2] = hig ? b2 : a2;
                    w[qb][3] = hig ? b3 : a3;
                }
                // ---- O^T += V^T P^T for this kk
                #pragma unroll
                for (int db = 0; db < 8; ++db) {
                    bf16x8 vf = *reinterpret_cast<const bf16x8*>(
                        &Vs[(db * 16 + lr) * 64 + (((kk * 4 + g) ^ (lr & 7)) * 8)]);
                    #pragma unroll
                    for (int qb = 0; qb < 2; ++qb) {
                        bf16x8 pb = *reinterpret_cast<const bf16x8*>(&w[qb]);
                        o_acc[qb][db] = __builtin_amdgcn_mfma_f32_16x16x32_bf16(
                            vf, pb, o_acc[qb][db], 0, 0, 0);
                    }
                }
            }
        }
    }

    // ---- epilogue: normalize, store bf16 [b,s,h,d]; d contiguous per lane (r) -> 8B stores
    #pragma unroll
    for (int qb = 0; qb < 2; ++qb) {
        float inv = 1.f / l_run[qb];
        size_t rowb = ((size_t)(b * S_ + q0w + qb * 16 + lr) * NH_ + h) * HD_;
        #pragma unroll
        for (int db = 0; db < 8; ++db) {
            ushort4 o4;
            o4.x = f2bf(o_acc[qb][db][0] * inv);
            o4.y = f2bf(o_acc[qb][db][1] * inv);
            o4.z = f2bf(o_acc[qb][db][2] * inv);
            o4.w = f2bf(o_acc[qb][db][3] * inv);
            *reinterpret_cast<ushort4*>(&O[rowb + db * 16 + g * 4]) = o4;
        }
    }
}

// ---------------- launcher ----------------
extern "C" void kernel_launch(void* const* d_in, const int* in_sizes, int n_in,
                              void* d_out, int out_size, void* d_ws, size_t ws_size,
                              hipStream_t stream)
{
    const float* x  = (const float*)d_in[0];
    const float* wq = (const float*)d_in[1];
    const float* wk = (const float*)d_in[2];
    const float* wv = (const float*)d_in[3];
    const float* wo = (const float*)d_in[4];
    float* out = (float*)d_out;

    char* ws = (char*)d_ws;
    size_t off = 0;
    auto alloc = [&](size_t bytes) -> void* {
        void* p = ws + off;
        off += (bytes + 255) & ~(size_t)255;
        return p;
    };
    unsigned short* xb   = (unsigned short*)alloc((size_t)B_ * S_ * DIM_ * 2);
    unsigned short* wqkb = (unsigned short*)alloc((size_t)3072 * 2048 * 2);
    unsigned short* wvb  = (unsigned short*)alloc((size_t)1024 * 2048 * 2);
    unsigned short* wob  = (unsigned short*)alloc((size_t)DIM_ * DIM_ * 2);
    unsigned short* QKb  = (unsigned short*)alloc((size_t)B_ * S_ * 3072 * 2);
    unsigned short* Vtb  = (unsigned short*)alloc((size_t)1024 * B_ * S_ * 2);
    unsigned short* Ob   = (unsigned short*)alloc((size_t)B_ * S_ * NH_ * HD_ * 2);
    float* tab = (float*)alloc((size_t)S_ * 64 * 2 * 4);

    const int M = B_ * S_;  // 4096

    k_convert<<<20480, 256, 0, stream>>>(x, wq, wk, wv, wo, xb, wqkb, wvb, wob);
    k_rope_table<<<(S_ * 64 + 255) / 256, 256, 0, stream>>>(tab);
    k_gemm_qkv<<<1024, 256, 0, stream>>>(xb, wqkb, wvb, QKb, Vtb, tab);
    k_attn<<<B_ * NH_ * (S_ / 128), 256, 0, stream>>>(QKb, Vtb, Ob);
    k_gemm_bt_f32<<<(M / 128) * (2048 / 128), 256, 0, stream>>>(Ob, wob, out, M, 2048, 2048);

    (void)in_sizes; (void)n_in; (void)out_size; (void)ws_size;
}

// Round 5
// 234.119 us; speedup vs baseline: 2.2729x; 1.1206x over previous
//
#include <hip/hip_runtime.h>
#include <hip/hip_bf16.h>
#include <stdint.h>
#include <type_traits>

typedef __attribute__((ext_vector_type(4))) float   f32x4;
typedef __attribute__((ext_vector_type(8))) __bf16  bf16x8;
typedef __attribute__((ext_vector_type(4))) unsigned int u32x4;

#define B_   2
#define S_   2048
#define DIM_ 2048
#define NH_  16
#define NKV_ 8
#define HD_  128

__device__ inline unsigned short f2bf(float f) {
    unsigned u = __float_as_uint(f);
    unsigned r = (u + 0x7fffu + ((u >> 16) & 1u)) >> 16;
    return (unsigned short)r;
}
__device__ inline float bf2f(unsigned short s) {
    return __uint_as_float(((unsigned)s) << 16);
}

// ---------------- fused fp32 -> bf16 convert (x, wq|wk stacked, wv, wo) ----------------
__global__ void k_convert(const float* __restrict__ x,  const float* __restrict__ wq,
                          const float* __restrict__ wk, const float* __restrict__ wv,
                          const float* __restrict__ wo,
                          unsigned short* __restrict__ xb,  unsigned short* __restrict__ wqkb,
                          unsigned short* __restrict__ wvb, unsigned short* __restrict__ wob)
{
    int i = blockIdx.x * blockDim.x + threadIdx.x;  // quad index
    const int NX = 2097152, NWQ = 1048576, NWK = 524288, NWV = 524288, NWO = 1048576;
    const float* src; unsigned short* dst; int j = i;
    if (j < NX) { src = x; dst = xb; }
    else {
        j -= NX;
        if (j < NWQ) { src = wq; dst = wqkb; }
        else {
            j -= NWQ;
            if (j < NWK) { src = wk; dst = wqkb + (size_t)2048 * 2048; }
            else {
                j -= NWK;
                if (j < NWV) { src = wv; dst = wvb; }
                else { j -= NWV; if (j >= NWO) return; src = wo; dst = wob; }
            }
        }
    }
    float4 v = reinterpret_cast<const float4*>(src)[j];
    ushort4 o;
    o.x = f2bf(v.x); o.y = f2bf(v.y); o.z = f2bf(v.z); o.w = f2bf(v.w);
    reinterpret_cast<ushort4*>(dst)[j] = o;
}

// ---------------- RoPE cos/sin table: [S][64] float2 ----------------
__global__ void k_rope_table(float* __restrict__ tab)
{
    int t = blockIdx.x * blockDim.x + threadIdx.x;  // s*64 + i
    if (t >= S_ * 64) return;
    int i = t & 63;
    int s = t >> 6;
    float inv = expf(-((float)i / 64.0f) * 9.210340371976184f);  // 10000^(-i/64)
    float ang = (float)s * inv;
    tab[2 * t]     = cosf(ang);
    tab[2 * t + 1] = sinf(ang);
}

// ================= 256x256 8-phase GEMM (T2+T3+T4+T5), K=2048 =================
// 512 threads = 8 waves (2M x 4N); per-wave out 128x64; BK=64; LDS 128 KiB
// (A: 2 bufs @ [256][64], B: 2 bufs @ [256][64], chunk-XOR swizzled).
// Per phase: {ds_read subtile || stage 1 half-tile; barrier; lgkmcnt(0);
// setprio(1); 16 MFMA; setprio(0); barrier}. vmcnt(4) only at phases 4,8.
// Stage schedule (iteration i computes tiles a=2i (buf0), b=2i+1 (buf1)):
//   P1:A1(2i+1) P2:B1(2i+1) P3:B0(2i+2) P4:A0(2i+2)+vm4
//   P5:A1(2i+2) P6:B1(2i+2) P7:B0(2i+3) P8:A0(2i+3)+vm4
// Overwrite-safety: each target's previous content last read >=1 barrier earlier.

#define BAR  __builtin_amdgcn_s_barrier()
#define WLG  asm volatile("s_waitcnt lgkmcnt(0)" ::: "memory")
#define WVM4 asm volatile("s_waitcnt vmcnt(4)" ::: "memory")
#define WVM0 asm volatile("s_waitcnt vmcnt(0)" ::: "memory")

#define G_LDS(SRC, DST) __builtin_amdgcn_global_load_lds( \
    (const __attribute__((address_space(1))) void*)(SRC), \
    (__attribute__((address_space(3))) void*)(DST), 16, 0, 0)

#define STAGE(MATB, DBUF, HALF, KT) do { \
    const unsigned short* _s0 = ((MATB) ? pb0 : pa0) + (size_t)(HALF) * 128 * 2048 + (KT) * 64; \
    const unsigned short* _s1 = ((MATB) ? pb1 : pa1) + (size_t)(HALF) * 128 * 2048 + (KT) * 64; \
    G_LDS(_s0, lds + (MATB) * 32768 + (DBUF) * 16384 + (HALF) * 8192 + lo0); \
    G_LDS(_s1, lds + (MATB) * 32768 + (DBUF) * 16384 + (HALF) * 8192 + lo1); \
} while (0)

#define LDA(DBUF, MH) { \
    _Pragma("unroll") \
    for (int mf = 0; mf < 4; ++mf) { \
        _Pragma("unroll") \
        for (int kk = 0; kk < 2; ++kk) { \
            const int R = wm * 128 + (MH) * 64 + mf * 16 + lr; \
            afr[MH][mf][kk] = *reinterpret_cast<const bf16x8*>( \
                &lds[(DBUF) * 16384 + R * 64 + (((kk * 4 + g) ^ (lr & 7)) * 8)]); \
        } } }

#define LDB(DBUF, NH) { \
    _Pragma("unroll") \
    for (int nf = 0; nf < 2; ++nf) { \
        _Pragma("unroll") \
        for (int kk = 0; kk < 2; ++kk) { \
            const int R = wn * 64 + (NH) * 32 + nf * 16 + lr; \
            bfr[NH][nf][kk] = *reinterpret_cast<const bf16x8*>( \
                &lds[32768 + (DBUF) * 16384 + R * 64 + (((kk * 4 + g) ^ (lr & 7)) * 8)]); \
        } } }

#define MMA(MH, NH) { \
    __builtin_amdgcn_s_setprio(1); \
    _Pragma("unroll") \
    for (int mf = 0; mf < 4; ++mf) { \
        _Pragma("unroll") \
        for (int nf = 0; nf < 2; ++nf) { \
            _Pragma("unroll") \
            for (int kk = 0; kk < 2; ++kk) \
                acc[(MH) * 4 + mf][(NH) * 2 + nf] = __builtin_amdgcn_mfma_f32_16x16x32_bf16( \
                    afr[MH][mf][kk], bfr[NH][nf][kk], acc[(MH) * 4 + mf][(NH) * 2 + nf], 0, 0, 0); \
        } } \
    __builtin_amdgcn_s_setprio(0); }

// MODE 0: fused QKV (blocks 0..191 QK w/ RoPE epi; 192..255 V^T), grid 256
// MODE 1: out-projection (f32 epi), grid 128
template <int MODE>
__global__ __launch_bounds__(512, 2) void k_gemm256(
    const unsigned short* __restrict__ A0g, const unsigned short* __restrict__ B0g,
    const unsigned short* __restrict__ A1g, const unsigned short* __restrict__ B1g,
    unsigned short* __restrict__ Cq, unsigned short* __restrict__ Cv,
    float* __restrict__ Cf, const float* __restrict__ tab)
{
    __shared__ __attribute__((aligned(16))) unsigned short lds[65536];  // 128 KiB

    const int tid  = threadIdx.x;
    const int lane = tid & 63;
    const int wid  = tid >> 6;
    const int g    = lane >> 4;
    const int lr   = lane & 15;
    const int wm   = wid >> 2;
    const int wn   = wid & 3;

    const unsigned short *Ag, *Bg;
    int brow, bcol;
    bool isQK = true;
    if constexpr (MODE == 0) {
        int swz = (blockIdx.x & 7) * 32 + (blockIdx.x >> 3);   // bijective, nwg=256
        if (swz < 192) { Ag = A0g; Bg = B0g; brow = (swz / 12) << 8; bcol = (swz % 12) << 8; }
        else { int ix = swz - 192; isQK = false; Ag = A1g; Bg = B1g; brow = (ix >> 4) << 8; bcol = (ix & 15) << 8; }
    } else {
        int swz = (blockIdx.x & 7) * 16 + (blockIdx.x >> 3);   // bijective, nwg=128
        Ag = A0g; Bg = B0g; brow = (swz >> 3) << 8; bcol = (swz & 7) << 8;
    }

    // staging constants: lane's two 16B slots, pre-swizzled global column
    const int E0 = wid * 512 + lane * 8;
    const int E1 = E0 + 4096;
    const int r0 = E0 >> 6, r1 = E1 >> 6;
    const int c0 = ((((E0 >> 3) & 7) ^ (r0 & 7)) * 8);
    const int c1 = ((((E1 >> 3) & 7) ^ (r1 & 7)) * 8);
    const unsigned short* pa0 = Ag + (size_t)(brow + r0) * 2048 + c0;
    const unsigned short* pa1 = Ag + (size_t)(brow + r1) * 2048 + c1;
    const unsigned short* pb0 = Bg + (size_t)(bcol + r0) * 2048 + c0;
    const unsigned short* pb1 = Bg + (size_t)(bcol + r1) * 2048 + c1;
    const int lo0 = wid * 512;
    const int lo1 = lo0 + 4096;

    f32x4 acc[8][4] = {};
    bf16x8 afr[2][4][2];
    bf16x8 bfr[2][2][2];

    // prologue: tile0 (A0,A1,B0,B1) -> buf0; tile1 (A0,B0) -> buf1
    STAGE(0, 0, 0, 0); STAGE(0, 0, 1, 0); STAGE(1, 0, 0, 0); STAGE(1, 0, 1, 0);
    STAGE(0, 1, 0, 1); STAGE(1, 1, 0, 1);
    WVM0; BAR;

    #pragma unroll 1
    for (int i = 0; i < 16; ++i) {
        const int kt1 = 2 * i + 1;
        int kt2 = 2 * i + 2;  if (kt2 >= 32) kt2 -= 32;
        int kt3 = 2 * i + 3;  if (kt3 >= 32) kt3 -= 32;
        // P1
        LDA(0, 0); LDB(0, 0);
        STAGE(0, 1, 1, kt1);
        BAR; WLG; MMA(0, 0); BAR;
        // P2
        LDA(0, 1);
        STAGE(1, 1, 1, kt1);
        BAR; WLG; MMA(1, 0); BAR;
        // P3
        LDB(0, 1);
        STAGE(1, 0, 0, kt2);
        BAR; WLG; MMA(0, 1); BAR;
        // P4
        STAGE(0, 0, 0, kt2);
        WVM4;
        BAR; WLG; MMA(1, 1); BAR;
        // P5
        LDA(1, 0); LDB(1, 0);
        STAGE(0, 0, 1, kt2);
        BAR; WLG; MMA(0, 0); BAR;
        // P6
        LDA(1, 1);
        STAGE(1, 0, 1, kt2);
        BAR; WLG; MMA(1, 0); BAR;
        // P7
        LDB(1, 1);
        STAGE(1, 1, 0, kt3);
        BAR; WLG; MMA(0, 1); BAR;
        // P8
        STAGE(0, 1, 0, kt3);
        WVM4;
        BAR; WLG; MMA(1, 1); BAR;
    }

    // -------- epilogue --------
    if constexpr (MODE == 1) {
        #pragma unroll
        for (int m = 0; m < 8; ++m)
            #pragma unroll
            for (int n = 0; n < 4; ++n)
                #pragma unroll
                for (int r = 0; r < 4; ++r) {
                    int row = brow + wm * 128 + (m >> 2) * 64 + (m & 3) * 16 + g * 4 + r;
                    int col = bcol + wn * 64 + (n >> 1) * 32 + (n & 1) * 16 + lr;
                    Cf[(size_t)row * 2048 + col] = acc[m][n][r];
                }
    } else if (isQK) {
        // RoPE fused: (even,odd) head-dim pairs live in adjacent lanes
        #pragma unroll
        for (int m = 0; m < 8; ++m) {
            #pragma unroll
            for (int n = 0; n < 4; ++n) {
                int col = bcol + wn * 64 + (n >> 1) * 32 + (n & 1) * 16 + lr;
                int ci  = (col & 127) >> 1;
                int row0 = brow + wm * 128 + (m >> 2) * 64 + (m & 3) * 16 + g * 4;
                #pragma unroll
                for (int r = 0; r < 4; ++r) {
                    int row = row0 + r;
                    int s   = row & (S_ - 1);
                    float2 cs = *reinterpret_cast<const float2*>(&tab[(s * 64 + ci) * 2]);
                    float v = acc[m][n][r];
                    float o = __shfl_xor(v, 1);
                    float res = (lane & 1) ? fmaf(o, cs.y, v * cs.x)
                                           : fmaf(v, cs.x, -(o * cs.y));
                    Cq[(size_t)row * 3072 + col] = f2bf(res);
                }
            }
        }
    } else {
        #pragma unroll
        for (int m = 0; m < 8; ++m)
            #pragma unroll
            for (int n = 0; n < 4; ++n)
                #pragma unroll
                for (int r = 0; r < 4; ++r) {
                    int row = brow + wm * 128 + (m >> 2) * 64 + (m & 3) * 16 + g * 4 + r;
                    int col = bcol + wn * 64 + (n >> 1) * 32 + (n & 1) * 16 + lr;
                    Cv[(size_t)row * 4096 + col] = f2bf(acc[m][n][r]);
                }
    }
}

// ---------------- flash attention (causal, GQA): swapped QK^T + in-reg softmax ----------------
__global__ __launch_bounds__(256, 2) void k_attn(
    const unsigned short* __restrict__ QK,
    const unsigned short* __restrict__ Vt,
    unsigned short* __restrict__ O)
{
    __shared__ __attribute__((aligned(16))) unsigned short Ks[64 * 128];
    __shared__ __attribute__((aligned(16))) unsigned short Vs[128 * 64];

    const int tid  = threadIdx.x;
    const int lane = tid & 63;
    const int wid  = tid >> 6;
    const int g    = lane >> 4;
    const int lr   = lane & 15;

    const int bid    = blockIdx.x;
    const int qt_raw = bid & 15;
    const int h      = (bid >> 4) & 15;
    const int b      = bid >> 8;
    const int qt     = b ? (15 - qt_raw) : qt_raw;   // balance co-resident pairs
    const int hk     = h >> 1;
    const int q0w    = qt * 128 + wid * 32;

    bf16x8 qf[2][4];
    #pragma unroll
    for (int qb = 0; qb < 2; ++qb)
        #pragma unroll
        for (int c = 0; c < 4; ++c)
            qf[qb][c] = *reinterpret_cast<const bf16x8*>(
                QK + (size_t)(b * S_ + q0w + qb * 16 + lr) * 3072 + h * HD_ + c * 32 + g * 8);

    f32x4 o_acc[2][8] = {};
    float m_run[2] = {-INFINITY, -INFINITY};
    float l_run[2] = {0.f, 0.f};

    const float C2 = 1.4426950408889634f * 0.08838834764831845f;  // log2e/sqrt(128)
    const int nt = 2 * qt + 2;
    const int srcb = (g & 1) * 32 + lr;
    const bool hig = g >> 1;

    for (int t = 0; t < nt; ++t) {
        const int kv0 = t * 64;
        __syncthreads();
        #pragma unroll
        for (int i4 = 0; i4 < 4; ++i4) {
            const int base = (i4 * 4 + wid) * 512;
            const int E = base + lane * 8;
            {
                int row = E >> 7, ch = (E >> 3) & 15;
                int col = ((ch ^ (row & 15)) * 8);
                __builtin_amdgcn_global_load_lds(
                    (const __attribute__((address_space(1))) void*)(
                        QK + (size_t)(b * S_ + kv0 + row) * 3072 + 2048 + hk * HD_ + col),
                    (__attribute__((address_space(3))) void*)(Ks + base), 16, 0, 0);
            }
            {
                int d = E >> 6, ch = (E >> 3) & 7;
                int kv = ((ch ^ (d & 7)) * 8);
                __builtin_amdgcn_global_load_lds(
                    (const __attribute__((address_space(1))) void*)(
                        Vt + (size_t)(hk * HD_ + d) * (B_ * S_) + b * S_ + kv0 + kv),
                    (__attribute__((address_space(3))) void*)(Vs + base), 16, 0, 0);
            }
        }
        __syncthreads();

        const bool active = kv0 < q0w + 32;
        if (active) {
            f32x4 sv[2][4] = {};
            #pragma unroll
            for (int c = 0; c < 4; ++c)
                #pragma unroll
                for (int kvb = 0; kvb < 4; ++kvb) {
                    bf16x8 kf = *reinterpret_cast<const bf16x8*>(
                        &Ks[(kvb * 16 + lr) * 128 + (((c * 4 + g) ^ lr) * 8)]);
                    #pragma unroll
                    for (int qb = 0; qb < 2; ++qb)
                        sv[qb][kvb] = __builtin_amdgcn_mfma_f32_16x16x32_bf16(
                            kf, qf[qb][c], sv[qb][kvb], 0, 0, 0);
                }

            if (kv0 + 63 > q0w) {
                #pragma unroll
                for (int qb = 0; qb < 2; ++qb) {
                    int qg = q0w + qb * 16 + lr;
                    #pragma unroll
                    for (int kvb = 0; kvb < 4; ++kvb) {
                        int kvg0 = kv0 + kvb * 16 + g * 4;
                        #pragma unroll
                        for (int r = 0; r < 4; ++r)
                            if (kvg0 + r > qg) sv[qb][kvb][r] = -INFINITY;
                    }
                }
            }

            float mt[2];
            #pragma unroll
            for (int qb = 0; qb < 2; ++qb) {
                float a  = fmaxf(fmaxf(sv[qb][0][0], sv[qb][0][1]), fmaxf(sv[qb][0][2], sv[qb][0][3]));
                float c2 = fmaxf(fmaxf(sv[qb][1][0], sv[qb][1][1]), fmaxf(sv[qb][1][2], sv[qb][1][3]));
                float c3 = fmaxf(fmaxf(sv[qb][2][0], sv[qb][2][1]), fmaxf(sv[qb][2][2], sv[qb][2][3]));
                float c4 = fmaxf(fmaxf(sv[qb][3][0], sv[qb][3][1]), fmaxf(sv[qb][3][2], sv[qb][3][3]));
                float m0 = fmaxf(fmaxf(a, c2), fmaxf(c3, c4));
                m0 = fmaxf(m0, __shfl_xor(m0, 16));
                m0 = fmaxf(m0, __shfl_xor(m0, 32));
                mt[qb] = m0;
            }

            bool need = (mt[0] > m_run[0] + 90.5f) | (mt[1] > m_run[1] + 90.5f);
            if (__any(need)) {
                #pragma unroll
                for (int qb = 0; qb < 2; ++qb) {
                    float mn = fmaxf(m_run[qb], mt[qb]);
                    float al = exp2f((m_run[qb] - mn) * C2);
                    m_run[qb] = mn;
                    l_run[qb] *= al;
                    #pragma unroll
                    for (int db = 0; db < 8; ++db)
                        #pragma unroll
                        for (int r = 0; r < 4; ++r)
                            o_acc[qb][db][r] *= al;
                }
            }

            unsigned pk[2][4][2];
            #pragma unroll
            for (int qb = 0; qb < 2; ++qb) {
                float mb2 = m_run[qb] * C2;
                float rs = 0.f;
                #pragma unroll
                for (int kvb = 0; kvb < 4; ++kvb) {
                    float p0 = exp2f(fmaf(sv[qb][kvb][0], C2, -mb2));
                    float p1 = exp2f(fmaf(sv[qb][kvb][1], C2, -mb2));
                    float p2 = exp2f(fmaf(sv[qb][kvb][2], C2, -mb2));
                    float p3 = exp2f(fmaf(sv[qb][kvb][3], C2, -mb2));
                    rs += (p0 + p1) + (p2 + p3);
                    pk[qb][kvb][0] = (unsigned)f2bf(p0) | ((unsigned)f2bf(p1) << 16);
                    pk[qb][kvb][1] = (unsigned)f2bf(p2) | ((unsigned)f2bf(p3) << 16);
                }
                rs += __shfl_xor(rs, 16);
                rs += __shfl_xor(rs, 32);
                l_run[qb] += rs;
            }

            #pragma unroll
            for (int kk = 0; kk < 2; ++kk) {
                u32x4 w[2];
                #pragma unroll
                for (int qb = 0; qb < 2; ++qb) {
                    unsigned a0 = (unsigned)__shfl((int)pk[qb][2 * kk][0], srcb);
                    unsigned a1 = (unsigned)__shfl((int)pk[qb][2 * kk][1], srcb);
                    unsigned a2 = (unsigned)__shfl((int)pk[qb][2 * kk][0], srcb + 16);
                    unsigned a3 = (unsigned)__shfl((int)pk[qb][2 * kk][1], srcb + 16);
                    unsigned b0 = (unsigned)__shfl((int)pk[qb][2 * kk + 1][0], srcb);
                    unsigned b1 = (unsigned)__shfl((int)pk[qb][2 * kk + 1][1], srcb);
                    unsigned b2 = (unsigned)__shfl((int)pk[qb][2 * kk + 1][0], srcb + 16);
                    unsigned b3 = (unsigned)__shfl((int)pk[qb][2 * kk + 1][1], srcb + 16);
                    w[qb][0] = hig ? b0 : a0;
                    w[qb][1] = hig ? b1 : a1;
                    w[qb][2] = hig ? b2 : a2;
                    w[qb][3] = hig ? b3 : a3;
                }
                #pragma unroll
                for (int db = 0; db < 8; ++db) {
                    bf16x8 vf = *reinterpret_cast<const bf16x8*>(
                        &Vs[(db * 16 + lr) * 64 + (((kk * 4 + g) ^ (lr & 7)) * 8)]);
                    #pragma unroll
                    for (int qb = 0; qb < 2; ++qb) {
                        bf16x8 pb = *reinterpret_cast<const bf16x8*>(&w[qb]);
                        o_acc[qb][db] = __builtin_amdgcn_mfma_f32_16x16x32_bf16(
                            vf, pb, o_acc[qb][db], 0, 0, 0);
                    }
                }
            }
        }
    }

    #pragma unroll
    for (int qb = 0; qb < 2; ++qb) {
        float inv = 1.f / l_run[qb];
        size_t rowb = ((size_t)(b * S_ + q0w + qb * 16 + lr) * NH_ + h) * HD_;
        #pragma unroll
        for (int db = 0; db < 8; ++db) {
            ushort4 o4;
            o4.x = f2bf(o_acc[qb][db][0] * inv);
            o4.y = f2bf(o_acc[qb][db][1] * inv);
            o4.z = f2bf(o_acc[qb][db][2] * inv);
            o4.w = f2bf(o_acc[qb][db][3] * inv);
            *reinterpret_cast<ushort4*>(&O[rowb + db * 16 + g * 4]) = o4;
        }
    }
}

// ---------------- launcher ----------------
extern "C" void kernel_launch(void* const* d_in, const int* in_sizes, int n_in,
                              void* d_out, int out_size, void* d_ws, size_t ws_size,
                              hipStream_t stream)
{
    const float* x  = (const float*)d_in[0];
    const float* wq = (const float*)d_in[1];
    const float* wk = (const float*)d_in[2];
    const float* wv = (const float*)d_in[3];
    const float* wo = (const float*)d_in[4];
    float* out = (float*)d_out;

    char* ws = (char*)d_ws;
    size_t off = 0;
    auto alloc = [&](size_t bytes) -> void* {
        void* p = ws + off;
        off += (bytes + 255) & ~(size_t)255;
        return p;
    };
    unsigned short* xb   = (unsigned short*)alloc((size_t)B_ * S_ * DIM_ * 2);
    unsigned short* wqkb = (unsigned short*)alloc((size_t)3072 * 2048 * 2);
    unsigned short* wvb  = (unsigned short*)alloc((size_t)1024 * 2048 * 2);
    unsigned short* wob  = (unsigned short*)alloc((size_t)DIM_ * DIM_ * 2);
    unsigned short* QKb  = (unsigned short*)alloc((size_t)B_ * S_ * 3072 * 2);
    unsigned short* Vtb  = (unsigned short*)alloc((size_t)1024 * B_ * S_ * 2);
    unsigned short* Ob   = (unsigned short*)alloc((size_t)B_ * S_ * NH_ * HD_ * 2);
    float* tab = (float*)alloc((size_t)S_ * 64 * 2 * 4);

    k_convert<<<20480, 256, 0, stream>>>(x, wq, wk, wv, wo, xb, wqkb, wvb, wob);
    k_rope_table<<<(S_ * 64 + 255) / 256, 256, 0, stream>>>(tab);
    k_gemm256<0><<<256, 512, 0, stream>>>(xb, wqkb, wvb, xb, QKb, Vtb, nullptr, tab);
    k_attn<<<B_ * NH_ * (S_ / 128), 256, 0, stream>>>(QKb, Vtb, Ob);
    k_gemm256<1><<<128, 512, 0, stream>>>(Ob, wob, nullptr, nullptr, nullptr, nullptr, out, tab);

    (void)in_sizes; (void)n_in; (void)out_size; (void)ws_size;
}